// Round 4
// baseline (650.943 us; speedup 1.0000x reference)
//
#include <hip/hip_runtime.h>

// ---------------------------------------------------------------------------
// 2-layer GCN, symmetric norm + self loops — fully scalarized form.
//
// feat is [n,1]  =>  layer-1 input to each node is a scalar. With b1 == 0
// (checked on device at runtime), relu(W1c * px) is RANK-2 over the fixed
// basis (relu(px), relu(-px)):
//     y[u,c] = w+_c * relu(px_u) + w-_c * relu(-px_u),  w± = max(±W1, 0)
// so layer 2 needs only TWO scalar segment-sums:
//     S±_v = q±_v + Σ_{s->v} q±_s,   q± = dinv * relu(±px)
//     out[v,k] = relu( dinv_v * (S+_v * u+[k] + S-_v * u-[k]) + b2[k] )
// with u± = w± @ W2 (2 x 64, precomputed once per call).
//
// Graph work = 3 thread-per-edge passes with native global atomics into
// 400-800KB L2-resident accumulators (no sort, no CSR, no serial gather
// chains — R3's k_l2 was latency-bound on its per-node dependent-load chain).
// A correct general-b1 fallback (32-wide y aggregation + dense epilogue) is
// device-flag-gated and exits immediately when b1 == 0.
// ---------------------------------------------------------------------------

#define TPB 256

// Detect int64 (low/high pairs) vs int32 edge layout: node ids < 2^31 so
// int64 high words are exactly 0. Sample odd 32-bit positions.
__global__ void k_detect(const int* __restrict__ e32, int E, int* __restrict__ flag) {
    __shared__ int ok;
    if (threadIdx.x == 0) ok = 1;
    __syncthreads();
    int stride = E / 2048; if (stride < 1) stride = 1;
    bool bad = false;
#pragma unroll
    for (int i = 0; i < 8; ++i) {
        long k = (long)(threadIdx.x * 8 + i) * stride + 1;
        if (k < E && e32[2 * k + 1] != 0) bad = true;
    }
    if (bad) atomicAnd(&ok, 0);
    __syncthreads();
    if (threadIdx.x == 0) *flag = ok;   // 1 => int64 (shift 1), 0 => int32
}

// u±[k] = sum_c max(±W1[c],0) * W2[c,k]; bzero = all(b1 == 0). One block, 64 thr.
__global__ void k_uv(const float* __restrict__ W1, const float* __restrict__ b1,
                     const float* __restrict__ W2, float* __restrict__ upm,
                     int* __restrict__ bzero) {
    __shared__ float sw[32], sb[32];
    int k = threadIdx.x;
    if (k < 32) { sw[k] = W1[k]; sb[k] = b1[k]; }
    __syncthreads();
    float up = 0.f, um = 0.f;
#pragma unroll
    for (int c = 0; c < 32; ++c) {
        float w = sw[c];
        float w2 = W2[c * 64 + k];
        up = fmaf(fmaxf(w, 0.f), w2, up);
        um = fmaf(fmaxf(-w, 0.f), w2, um);
    }
    upm[k] = up;
    upm[64 + k] = um;
    if (k == 0) {
        int z = 1;
        for (int c = 0; c < 32; ++c) if (sb[c] != 0.f) z = 0;
        *bzero = z;
    }
}

__global__ void k_zero(int* __restrict__ p, int n) {
    int i = blockIdx.x * TPB + threadIdx.x;
    if (i < n) p[i] = 0;
}

// pass 1: in-degree counts
__global__ void k_count(const int* __restrict__ e32, const int* __restrict__ flag,
                        int E, int* __restrict__ cnt) {
    int sh = *flag;
    long stride = (long)gridDim.x * TPB;
    for (long e = (long)blockIdx.x * TPB + threadIdx.x; e < E; e += stride) {
        int d = e32[((long)E + e) << sh];
        atomicAdd(&cnt[d], 1);
    }
}

// dinv, g = dinv*feat, Aacc init with self term
__global__ void k_prep1(const float* __restrict__ feat, const int* __restrict__ cnt,
                        int n, float* __restrict__ dinv, float* __restrict__ g,
                        float* __restrict__ Aacc) {
    int v = blockIdx.x * TPB + threadIdx.x;
    if (v >= n) return;
    float di = rsqrtf((float)(cnt[v] + 1));
    dinv[v] = di;
    float gv = di * feat[v];
    g[v] = gv;
    Aacc[v] = gv;
}

// pass 2: A_v += g[src]
__global__ void k_aggA(const int* __restrict__ e32, const int* __restrict__ flag,
                       int E, const float* __restrict__ g, float* __restrict__ Aacc) {
    int sh = *flag;
    long stride = (long)gridDim.x * TPB;
    for (long e = (long)blockIdx.x * TPB + threadIdx.x; e < E; e += stride) {
        int s = e32[e << sh];
        int d = e32[((long)E + e) << sh];
        atomicAdd(&Aacc[d], g[s]);
    }
}

// px = dinv*A; q± = dinv*relu(±px); T2 init with self term; pd for general path
__global__ void k_prep2(const float* __restrict__ dinv, const float* __restrict__ Aacc,
                        int n, const int* __restrict__ bzero,
                        float2* __restrict__ q2, float2* __restrict__ T2,
                        float2* __restrict__ pd, float* __restrict__ Yagg) {
    int v = blockIdx.x * TPB + threadIdx.x;
    if (v >= n) return;
    float di = dinv[v];
    float px = di * Aacc[v];
    float qp = di * fmaxf(px, 0.f);
    float qm = di * fmaxf(-px, 0.f);
    q2[v] = make_float2(qp, qm);
    T2[v] = make_float2(qp, qm);
    pd[v] = make_float2(px, di);
    if (!*bzero) {                       // general path: zero the 32-wide acc
        float4* Y = (float4*)(Yagg + (size_t)v * 32);
#pragma unroll
        for (int i = 0; i < 8; ++i) Y[i] = make_float4(0.f, 0.f, 0.f, 0.f);
    }
}

// pass 3 (fast): S± += q±[src]
__global__ void k_aggT(const int* __restrict__ e32, const int* __restrict__ flag,
                       int E, const int* __restrict__ bzero,
                       const float2* __restrict__ q2, float2* __restrict__ T2) {
    if (!*bzero) return;
    int sh = *flag;
    long stride = (long)gridDim.x * TPB;
    for (long e = (long)blockIdx.x * TPB + threadIdx.x; e < E; e += stride) {
        int s = e32[e << sh];
        int d = e32[((long)E + e) << sh];
        float2 q = q2[s];
        atomicAdd(&T2[d].x, q.x);
        atomicAdd(&T2[d].y, q.y);
    }
}

// pass 3 (general b1 != 0): Yagg[d,c] += dinv_s * relu(W1c*px_s + b1c*dinv_s)
__global__ void k_aggY(const int* __restrict__ e32, const int* __restrict__ flag,
                       int E, const int* __restrict__ bzero,
                       const float2* __restrict__ pd,
                       const float* __restrict__ W1, const float* __restrict__ b1,
                       float* __restrict__ Yagg) {
    if (*bzero) return;                  // uniform across all threads
    __shared__ float sw[32], sb[32];
    if (threadIdx.x < 32) { sw[threadIdx.x] = W1[threadIdx.x]; sb[threadIdx.x] = b1[threadIdx.x]; }
    __syncthreads();
    int sh = *flag;
    long stride = (long)gridDim.x * TPB;
    for (long e = (long)blockIdx.x * TPB + threadIdx.x; e < E; e += stride) {
        int s = e32[e << sh];
        int d = e32[((long)E + e) << sh];
        float2 p = pd[s];
#pragma unroll
        for (int c = 0; c < 32; ++c) {
            float y = p.y * fmaxf(fmaf(sw[c], p.x, sb[c] * p.y), 0.f);
            atomicAdd(&Yagg[(size_t)d * 32 + c], y);
        }
    }
}

// epilogue (fast): out[v,k] = relu(dinv_v*(S+ u+[k] + S- u-[k]) + b2[k])
__global__ void k_final_fast(const float* __restrict__ dinv, const float2* __restrict__ T2,
                             const float* __restrict__ upm, const float* __restrict__ b2,
                             const int* __restrict__ bzero, int n, float* __restrict__ out) {
    if (!*bzero) return;
    int tid = blockIdx.x * TPB + threadIdx.x;
    int v = tid >> 6, k = tid & 63;
    if (v >= n) return;
    float2 S = T2[v];
    float o = fmaf(dinv[v], fmaf(S.x, upm[k], S.y * upm[64 + k]), b2[k]);
    out[(size_t)v * 64 + k] = fmaxf(o, 0.f);
}

// epilogue (general): 8 nodes/block, dense 32x64 matmul from LDS
__global__ void k_final_gen(const float2* __restrict__ pd, const float* __restrict__ Yagg,
                            const float* __restrict__ W1, const float* __restrict__ b1,
                            const float* __restrict__ W2, const float* __restrict__ b2,
                            const int* __restrict__ bzero, int n, float* __restrict__ out) {
    if (*bzero) return;
    __shared__ float sW[32 * 64];
    __shared__ float sb2[64];
    __shared__ float sagg[8][33];
    int t = threadIdx.x;
    for (int i = t; i < 32 * 64; i += TPB) sW[i] = W2[i];
    if (t < 64) sb2[t] = b2[t];
    int vl = t >> 5, c = t & 31;
    int v = blockIdx.x * 8 + vl;
    float a = 0.f, dv = 0.f;
    if (v < n) {
        float2 p = pd[v];
        dv = p.y;
        float yv = fmaxf(fmaf(W1[c], p.x, b1[c] * p.y), 0.f);
        a = dv * (dv * yv + Yagg[(size_t)v * 32 + c]);
    }
    __syncthreads();
    sagg[vl][c] = a;
    __syncthreads();
    if (v < n) {
        float o0 = sb2[c], o1 = sb2[c + 32];
#pragma unroll
        for (int j = 0; j < 32; ++j) {
            float x = sagg[vl][j];
            o0 += x * sW[j * 64 + c];
            o1 += x * sW[j * 64 + 32 + c];
        }
        out[(size_t)v * 64 + c]      = fmaxf(o0, 0.f);
        out[(size_t)v * 64 + 32 + c] = fmaxf(o1, 0.f);
    }
}

static inline size_t align256(size_t x) { return (x + 255) & ~(size_t)255; }

extern "C" void kernel_launch(void* const* d_in, const int* in_sizes, int n_in,
                              void* d_out, int out_size, void* d_ws, size_t ws_size,
                              hipStream_t stream) {
    const float* feat = (const float*)d_in[0];
    const int*   e32  = (const int*)d_in[1];
    const float* W1   = (const float*)d_in[2];
    const float* b1   = (const float*)d_in[3];
    const float* W2   = (const float*)d_in[4];
    const float* b2   = (const float*)d_in[5];
    float* out = (float*)d_out;

    int n = in_sizes[0];         // 100000
    int E = in_sizes[1] / 2;     // 3200000

    char* w = (char*)d_ws;
    size_t off = 0;
    auto alloc = [&](size_t bytes) -> char* { char* p = w + off; off = align256(off + bytes); return p; };
    int*    cnt   = (int*)alloc((size_t)n * 4);
    float*  dinv  = (float*)alloc((size_t)n * 4);
    float*  g     = (float*)alloc((size_t)n * 4);
    float*  Aacc  = (float*)alloc((size_t)n * 4);
    float2* q2    = (float2*)alloc((size_t)n * 8);
    float2* T2    = (float2*)alloc((size_t)n * 8);
    float2* pd    = (float2*)alloc((size_t)n * 8);
    float*  upm   = (float*)alloc(128 * 4);
    int*    flag  = (int*)alloc(4);
    int*    bzero = (int*)alloc(4);
    float*  Yagg  = (float*)alloc((size_t)n * 32 * 4);   // general path only

    int gN  = (n + TPB - 1) / TPB;
    int gE  = 2048;                                      // grid-stride edge passes
    int gF  = (n * 64 + TPB - 1) / TPB;
    int gG  = (n + 7) / 8;

    hipLaunchKernelGGL(k_detect,     dim3(1),   dim3(TPB), 0, stream, e32, E, flag);
    hipLaunchKernelGGL(k_uv,         dim3(1),   dim3(64),  0, stream, W1, b1, W2, upm, bzero);
    hipLaunchKernelGGL(k_zero,       dim3(gN),  dim3(TPB), 0, stream, cnt, n);
    hipLaunchKernelGGL(k_count,      dim3(gE),  dim3(TPB), 0, stream, e32, flag, E, cnt);
    hipLaunchKernelGGL(k_prep1,      dim3(gN),  dim3(TPB), 0, stream, feat, cnt, n, dinv, g, Aacc);
    hipLaunchKernelGGL(k_aggA,       dim3(gE),  dim3(TPB), 0, stream, e32, flag, E, g, Aacc);
    hipLaunchKernelGGL(k_prep2,      dim3(gN),  dim3(TPB), 0, stream, dinv, Aacc, n, bzero, q2, T2, pd, Yagg);
    hipLaunchKernelGGL(k_aggT,       dim3(gE),  dim3(TPB), 0, stream, e32, flag, E, bzero, q2, T2);
    hipLaunchKernelGGL(k_aggY,       dim3(gE),  dim3(TPB), 0, stream, e32, flag, E, bzero, pd, W1, b1, Yagg);
    hipLaunchKernelGGL(k_final_fast, dim3(gF),  dim3(TPB), 0, stream, dinv, T2, upm, b2, bzero, n, out);
    hipLaunchKernelGGL(k_final_gen,  dim3(gG),  dim3(TPB), 0, stream, pd, Yagg, W1, b1, W2, b2, bzero, n, out);
}

// Round 5
// 161.675 us; speedup vs baseline: 4.0262x; 4.0262x over previous
//
#include <hip/hip_runtime.h>

// ---------------------------------------------------------------------------
// 2-layer GCN, symmetric norm + self loops — rank-2 scalarized, LDS-atomic
// segment sums over a coarse dst-bucket partition.
//
// feat is [n,1] and b1 == 0 (device-checked)  =>
//   px_v = dinv_v * (g_v + sum g_src),  g = dinv*feat
//   y[u,c] = w+_c relu(px_u) + w-_c relu(-px_u)         (rank-2, w± = max(±W1,0))
//   out[v,k] = relu( dinv_v (S+_v u+[k] + S-_v u-[k]) + b2[k] ),
//   S±_v = q±_v + sum q±_src,  q± = dinv relu(±px),  u± = w± @ W2 (2x64)
//
// R4 lesson: device-scope f32 atomics cost ~32B HBM writeback EACH (6.4M
// atomics -> 200MB WRITE_SIZE). So all segment sums here are LDS atomics
// inside dst-buckets (64 nodes/bucket, partitioned once via the proven
// clustered-scatter pattern). No CSR sort, no per-node serial gather chains.
// General-b1 fallback (global-atomic path) is flag-gated; never runs in bench.
// ---------------------------------------------------------------------------

#define TPB 256
#define NSBMAX 4096   // max buckets (LDS hist in k_hist/k_part)
#define SBSZMAX 256   // max nodes per bucket

// Detect int64 (low/high pairs) vs int32 edge layout: ids < 2^31 so int64
// high words are exactly 0. Sample odd 32-bit positions.
__global__ void k_detect(const int* __restrict__ e32, int E, int* __restrict__ flag) {
    __shared__ int ok;
    if (threadIdx.x == 0) ok = 1;
    __syncthreads();
    int stride = E / 2048; if (stride < 1) stride = 1;
    bool bad = false;
#pragma unroll
    for (int i = 0; i < 8; ++i) {
        long k = (long)(threadIdx.x * 8 + i) * stride + 1;
        if (k < E && e32[2 * k + 1] != 0) bad = true;
    }
    if (bad) atomicAnd(&ok, 0);
    __syncthreads();
    if (threadIdx.x == 0) *flag = ok;   // 1 => int64 (shift 1), 0 => int32
}

// u±[k] = sum_c max(±W1[c],0) * W2[c,k]; bzero = all(b1==0). 1 block, 64 thr.
__global__ void k_uv(const float* __restrict__ W1, const float* __restrict__ b1,
                     const float* __restrict__ W2, float* __restrict__ upm,
                     int* __restrict__ bzero) {
    __shared__ float sw[32], sb[32];
    int k = threadIdx.x;
    if (k < 32) { sw[k] = W1[k]; sb[k] = b1[k]; }
    __syncthreads();
    float up = 0.f, um = 0.f;
#pragma unroll
    for (int c = 0; c < 32; ++c) {
        float w = sw[c];
        float w2 = W2[c * 64 + k];
        up = fmaf(fmaxf(w, 0.f), w2, up);
        um = fmaf(fmaxf(-w, 0.f), w2, um);
    }
    upm[k] = up;
    upm[64 + k] = um;
    if (k == 0) {
        int z = 1;
        for (int c = 0; c < 32; ++c) if (sb[c] != 0.f) z = 0;
        *bzero = z;
    }
}

__global__ void k_zero(int* __restrict__ p, int n) {
    int i = blockIdx.x * TPB + threadIdx.x;
    if (i < n) p[i] = 0;
}

// global bucket histogram (LDS-staged; few global int atomics)
__global__ void k_hist(const int* __restrict__ e32, const int* __restrict__ flag,
                       int E, int NSB, int lbits, int* __restrict__ gHist) {
    __shared__ int sh[NSBMAX];
    for (int i = threadIdx.x; i < NSB; i += TPB) sh[i] = 0;
    __syncthreads();
    int f = *flag;
    long stride = (long)gridDim.x * TPB;
    for (long e = (long)blockIdx.x * TPB + threadIdx.x; e < E; e += stride) {
        int d = e32[((long)E + e) << f];
        atomicAdd(&sh[d >> lbits], 1);
    }
    __syncthreads();
    for (int i = threadIdx.x; i < NSB; i += TPB)
        if (sh[i]) atomicAdd(&gHist[i], sh[i]);
}

// one-block exclusive scan of NSB bucket counts -> base, cursor
__global__ void k_scan(const int* __restrict__ gHist, int NSB, int E,
                       int* __restrict__ base, int* __restrict__ cursor) {
    __shared__ int s[TPB];
    int K = (NSB + TPB - 1) / TPB;
    int t = threadIdx.x;
    int i0 = t * K;
    int tot = 0;
    for (int k = 0; k < K; ++k) { int i = i0 + k; if (i < NSB) tot += gHist[i]; }
    s[t] = tot;
    __syncthreads();
    for (int off = 1; off < TPB; off <<= 1) {
        int v = s[t];
        int u = (t >= off) ? s[t - off] : 0;
        __syncthreads();
        s[t] = v + u;
        __syncthreads();
    }
    int run = s[t] - tot;   // exclusive
    for (int k = 0; k < K; ++k) {
        int i = i0 + k;
        if (i < NSB) { int h = gHist[i]; base[i] = run; cursor[i] = run; run += h; }
    }
    if (t == 0) base[NSB] = E;
}

// partition edges bucket-major: per-chunk LDS hist -> one reservation atomic
// per (bucket,block) -> clustered scatter of packed (ldst<<sshift)|src.
__global__ void k_part(const int* __restrict__ e32, const int* __restrict__ flag,
                       int E, int NSB, int lbits, int* __restrict__ cursor,
                       unsigned int* __restrict__ P, int chunk) {
    __shared__ int sh[NSBMAX];
    int c0 = blockIdx.x * chunk;
    int c1 = c0 + chunk; if (c1 > E) c1 = E;
    for (int i = threadIdx.x; i < NSB; i += TPB) sh[i] = 0;
    __syncthreads();
    int f = *flag;
    for (int e = c0 + threadIdx.x; e < c1; e += TPB) {
        int d = e32[((long)E + e) << f];
        atomicAdd(&sh[d >> lbits], 1);
    }
    __syncthreads();
    for (int i = threadIdx.x; i < NSB; i += TPB) {
        int c = sh[i];
        sh[i] = c ? atomicAdd(&cursor[i], c) : 0;   // LDS cell now holds cursor
    }
    __syncthreads();
    int sshift = 32 - lbits;
    for (int e = c0 + threadIdx.x; e < c1; e += TPB) {
        long ee = (long)e << f;
        int s = e32[ee];
        int d = e32[(((long)E) << f) + ee];
        int b = d >> lbits;
        int pos = atomicAdd(&sh[b], 1);
        P[pos] = (unsigned)s | ((unsigned)(d & ((1 << lbits) - 1)) << sshift);
    }
}

// per bucket: LDS degree histogram -> dinv, g
__global__ void k_deg(const unsigned int* __restrict__ P, const int* __restrict__ base,
                      int lbits, int n, const float* __restrict__ feat,
                      float* __restrict__ dinv, float* __restrict__ g) {
    __shared__ int cnt[SBSZMAX];
    int b = blockIdx.x, t = threadIdx.x;
    int SBSZ = 1 << lbits;
    if (t < SBSZ) cnt[t] = 0;
    __syncthreads();
    int p0 = base[b], p1 = base[b + 1];
    int sshift = 32 - lbits;
    for (int p = p0 + t; p < p1; p += TPB)
        atomicAdd(&cnt[P[p] >> sshift], 1);
    __syncthreads();
    int v = (b << lbits) + t;
    if (t < SBSZ && v < n) {
        float di = rsqrtf((float)(cnt[t] + 1));
        dinv[v] = di;
        g[v] = di * feat[v];
    }
}

// per bucket: A_v = g_v + sum g_src (LDS float adds) -> px, q±, pd
__global__ void k_aggA(const unsigned int* __restrict__ P, const int* __restrict__ base,
                       int lbits, int n, const float* __restrict__ g,
                       const float* __restrict__ dinv, const int* __restrict__ bzero,
                       float2* __restrict__ q2, float2* __restrict__ pd,
                       float* __restrict__ Yagg) {
    __shared__ float A[SBSZMAX];
    int b = blockIdx.x, t = threadIdx.x;
    int SBSZ = 1 << lbits;
    int v = (b << lbits) + t;
    if (t < SBSZ) A[t] = (v < n) ? g[v] : 0.f;   // self term
    __syncthreads();
    int p0 = base[b], p1 = base[b + 1];
    int sshift = 32 - lbits;
    unsigned smask = (1u << sshift) - 1;
    for (int p = p0 + t; p < p1; p += TPB) {
        unsigned e = P[p];
        atomicAdd(&A[e >> sshift], g[e & smask]);
    }
    __syncthreads();
    if (t < SBSZ && v < n) {
        float di = dinv[v];
        float px = di * A[t];
        pd[v] = make_float2(px, di);
        q2[v] = make_float2(di * fmaxf(px, 0.f), di * fmaxf(-px, 0.f));
        if (!*bzero) {
            float4* Y = (float4*)(Yagg + (size_t)v * 32);
#pragma unroll
            for (int i = 0; i < 8; ++i) Y[i] = make_float4(0.f, 0.f, 0.f, 0.f);
        }
    }
}

// per bucket (fast, b1==0): S± = q±_v + sum q±_src (LDS adds), then fused
// epilogue: out[v,k] = relu(dinv (S+ u+[k] + S- u-[k]) + b2[k]), coalesced.
__global__ void k_aggT(const unsigned int* __restrict__ P, const int* __restrict__ base,
                       int lbits, int n, const float2* __restrict__ q2,
                       const float* __restrict__ dinv, const float* __restrict__ upm,
                       const float* __restrict__ b2, const int* __restrict__ bzero,
                       float* __restrict__ out) {
    if (!*bzero) return;
    __shared__ float Sp[SBSZMAX], Sm[SBSZMAX], Sd[SBSZMAX];
    __shared__ float su[192];    // u+ | u- | b2
    int b = blockIdx.x, t = threadIdx.x;
    int SBSZ = 1 << lbits;
    int v0 = b << lbits;
    int v = v0 + t;
    if (t < SBSZ) {
        if (v < n) { float2 q = q2[v]; Sp[t] = q.x; Sm[t] = q.y; Sd[t] = dinv[v]; }
        else       { Sp[t] = 0.f; Sm[t] = 0.f; Sd[t] = 0.f; }
    }
    if (t < 192) su[t] = (t < 128) ? upm[t] : b2[t - 128];
    __syncthreads();
    int p0 = base[b], p1 = base[b + 1];
    int sshift = 32 - lbits;
    unsigned smask = (1u << sshift) - 1;
    for (int p = p0 + t; p < p1; p += TPB) {
        unsigned e = P[p];
        float2 q = q2[e & smask];
        int l = e >> sshift;
        atomicAdd(&Sp[l], q.x);
        atomicAdd(&Sm[l], q.y);
    }
    __syncthreads();
    int nv = n - v0; if (nv > SBSZ) nv = SBSZ; if (nv < 0) nv = 0;
    for (int o = t; o < nv * 64; o += TPB) {
        int vl = o >> 6, k = o & 63;
        float r = fmaf(Sd[vl], fmaf(Sp[vl], su[k], Sm[vl] * su[64 + k]), su[128 + k]);
        out[(size_t)(v0 + vl) * 64 + k] = fmaxf(r, 0.f);
    }
}

// ---- general-b1 fallback (flag-gated; slow global-atomic path, never taken
// in this benchmark since b1 == 0) ----
__global__ void k_aggY(const int* __restrict__ e32, const int* __restrict__ flag,
                       int E, const int* __restrict__ bzero,
                       const float2* __restrict__ pd,
                       const float* __restrict__ W1, const float* __restrict__ b1,
                       float* __restrict__ Yagg) {
    if (*bzero) return;
    __shared__ float sw[32], sb[32];
    if (threadIdx.x < 32) { sw[threadIdx.x] = W1[threadIdx.x]; sb[threadIdx.x] = b1[threadIdx.x]; }
    __syncthreads();
    int sh = *flag;
    long stride = (long)gridDim.x * TPB;
    for (long e = (long)blockIdx.x * TPB + threadIdx.x; e < E; e += stride) {
        int s = e32[e << sh];
        int d = e32[((long)E + e) << sh];
        float2 p = pd[s];
#pragma unroll
        for (int c = 0; c < 32; ++c) {
            float y = p.y * fmaxf(fmaf(sw[c], p.x, sb[c] * p.y), 0.f);
            atomicAdd(&Yagg[(size_t)d * 32 + c], y);
        }
    }
}

__global__ void k_final_gen(const float2* __restrict__ pd, const float* __restrict__ Yagg,
                            const float* __restrict__ W1, const float* __restrict__ b1,
                            const float* __restrict__ W2, const float* __restrict__ b2,
                            const int* __restrict__ bzero, int n, float* __restrict__ out) {
    if (*bzero) return;
    __shared__ float sW[32 * 64];
    __shared__ float sb2[64];
    __shared__ float sagg[8][33];
    int t = threadIdx.x;
    for (int i = t; i < 32 * 64; i += TPB) sW[i] = W2[i];
    if (t < 64) sb2[t] = b2[t];
    int vl = t >> 5, c = t & 31;
    int v = blockIdx.x * 8 + vl;
    float a = 0.f;
    if (v < n) {
        float2 p = pd[v];
        float dv = p.y;
        float yv = fmaxf(fmaf(W1[c], p.x, b1[c] * p.y), 0.f);
        a = dv * (dv * yv + Yagg[(size_t)v * 32 + c]);
    }
    __syncthreads();
    sagg[vl][c] = a;
    __syncthreads();
    if (v < n) {
        float o0 = sb2[c], o1 = sb2[c + 32];
#pragma unroll
        for (int j = 0; j < 32; ++j) {
            float x = sagg[vl][j];
            o0 += x * sW[j * 64 + c];
            o1 += x * sW[j * 64 + 32 + c];
        }
        out[(size_t)v * 64 + c]      = fmaxf(o0, 0.f);
        out[(size_t)v * 64 + 32 + c] = fmaxf(o1, 0.f);
    }
}

static inline size_t align256(size_t x) { return (x + 255) & ~(size_t)255; }

extern "C" void kernel_launch(void* const* d_in, const int* in_sizes, int n_in,
                              void* d_out, int out_size, void* d_ws, size_t ws_size,
                              hipStream_t stream) {
    const float* feat = (const float*)d_in[0];
    const int*   e32  = (const int*)d_in[1];
    const float* W1   = (const float*)d_in[2];
    const float* b1   = (const float*)d_in[3];
    const float* W2   = (const float*)d_in[4];
    const float* b2   = (const float*)d_in[5];
    float* out = (float*)d_out;

    int n = in_sizes[0];         // 100000
    int E = in_sizes[1] / 2;     // 3200000

    int lbits = 6;                                        // 64 nodes / bucket
    while ((((n + (1 << lbits) - 1) >> lbits) > NSBMAX) && lbits < 8) lbits++;
    int NSB = (n + (1 << lbits) - 1) >> lbits;            // 1563 @ n=100K

    char* w = (char*)d_ws;
    size_t off = 0;
    auto alloc = [&](size_t bytes) -> char* { char* p = w + off; off = align256(off + bytes); return p; };
    unsigned int* P = (unsigned int*)alloc((size_t)E * 4);
    int*    gHist = (int*)alloc((size_t)NSB * 4);
    int*    base  = (int*)alloc((size_t)(NSB + 1) * 4);
    int*    cursor= (int*)alloc((size_t)NSB * 4);
    float*  dinv  = (float*)alloc((size_t)n * 4);
    float*  g     = (float*)alloc((size_t)n * 4);
    float2* q2    = (float2*)alloc((size_t)n * 8);
    float2* pd    = (float2*)alloc((size_t)n * 8);
    float*  upm   = (float*)alloc(128 * 4);
    int*    flag  = (int*)alloc(4);
    int*    bzero = (int*)alloc(4);
    float*  Yagg  = (float*)alloc((size_t)n * 32 * 4);    // general path only

    int chunk = (E + 255) / 256;
    int gC = (E + chunk - 1) / chunk;

    hipLaunchKernelGGL(k_detect,    dim3(1),    dim3(TPB), 0, stream, e32, E, flag);
    hipLaunchKernelGGL(k_uv,        dim3(1),    dim3(64),  0, stream, W1, b1, W2, upm, bzero);
    hipLaunchKernelGGL(k_zero,      dim3((NSB + TPB - 1) / TPB), dim3(TPB), 0, stream, gHist, NSB);
    hipLaunchKernelGGL(k_hist,      dim3(256),  dim3(TPB), 0, stream, e32, flag, E, NSB, lbits, gHist);
    hipLaunchKernelGGL(k_scan,      dim3(1),    dim3(TPB), 0, stream, gHist, NSB, E, base, cursor);
    hipLaunchKernelGGL(k_part,      dim3(gC),   dim3(TPB), 0, stream, e32, flag, E, NSB, lbits, cursor, P, chunk);
    hipLaunchKernelGGL(k_deg,       dim3(NSB),  dim3(TPB), 0, stream, P, base, lbits, n, feat, dinv, g);
    hipLaunchKernelGGL(k_aggA,      dim3(NSB),  dim3(TPB), 0, stream, P, base, lbits, n, g, dinv, bzero, q2, pd, Yagg);
    hipLaunchKernelGGL(k_aggT,      dim3(NSB),  dim3(TPB), 0, stream, P, base, lbits, n, q2, dinv, upm, b2, bzero, out);
    hipLaunchKernelGGL(k_aggY,      dim3(512),  dim3(TPB), 0, stream, e32, flag, E, bzero, pd, W1, b1, Yagg);
    hipLaunchKernelGGL(k_final_gen, dim3((n + 7) / 8), dim3(TPB), 0, stream, pd, Yagg, W1, b1, W2, b2, bzero, n, out);
}

// Round 6
// 150.513 us; speedup vs baseline: 4.3248x; 1.0742x over previous
//
#include <hip/hip_runtime.h>

// ---------------------------------------------------------------------------
// 2-layer GCN, symmetric norm + self loops — rank-2 scalarized, LDS-atomic
// segment sums over a coarse dst-bucket partition.
//
// feat is [n,1] and b1 == 0 (device-checked)  =>
//   px_v = dinv_v * (g_v + sum g_src),  g = dinv*feat
//   y[u,c] = w+_c relu(px_u) + w-_c relu(-px_u)         (rank-2, w± = max(±W1,0))
//   out[v,k] = relu( dinv_v (S+_v u+[k] + S-_v u-[k]) + b2[k] ),
//   S±_v = q±_v + sum q±_src,  q± = dinv relu(±px),  u± = w± @ W2 (2x64)
//
// R4 lesson: device-scope f32 atomics cost ~32B HBM writeback each -> all
// segment sums are LDS atomics inside dst-buckets.
// R5 lesson: the bucket partition's scatter was 7x write-amplified (8-edge
// = 32B runs per block per bucket) and ran at 1 block/CU. Fix: 256-node
// buckets (128B runs) + TPB=1024 partition kernel (16 waves/CU).
// ---------------------------------------------------------------------------

#define TPB 256
#define TPBP 1024     // partition kernel block size
#define NSBMAX 1024   // max buckets (LDS hist arrays)
#define SBSZ 256      // nodes per bucket (= 1 << LBITS)
#define LBITS 8

// Detect int64 (low/high pairs) vs int32 edge layout (ids < 2^31 => int64
// high words are 0; sample odd 32-bit positions). Also zeroes gHist.
__global__ void k_detect(const int* __restrict__ e32, int E, int* __restrict__ flag,
                         int* __restrict__ gHist, int NSB) {
    __shared__ int ok;
    if (threadIdx.x == 0) ok = 1;
    __syncthreads();
    for (int i = threadIdx.x; i < NSB; i += TPB) gHist[i] = 0;
    int stride = E / 2048; if (stride < 1) stride = 1;
    bool bad = false;
#pragma unroll
    for (int i = 0; i < 8; ++i) {
        long k = (long)(threadIdx.x * 8 + i) * stride + 1;
        if (k < E && e32[2 * k + 1] != 0) bad = true;
    }
    if (bad) atomicAnd(&ok, 0);
    __syncthreads();
    if (threadIdx.x == 0) *flag = ok;   // 1 => int64 (shift 1), 0 => int32
}

// u±[k] = sum_c max(±W1[c],0) * W2[c,k]; bzero = all(b1==0). 1 block, 64 thr.
__global__ void k_uv(const float* __restrict__ W1, const float* __restrict__ b1,
                     const float* __restrict__ W2, float* __restrict__ upm,
                     int* __restrict__ bzero) {
    __shared__ float sw[32], sb[32];
    int k = threadIdx.x;
    if (k < 32) { sw[k] = W1[k]; sb[k] = b1[k]; }
    __syncthreads();
    float up = 0.f, um = 0.f;
#pragma unroll
    for (int c = 0; c < 32; ++c) {
        float w = sw[c];
        float w2 = W2[c * 64 + k];
        up = fmaf(fmaxf(w, 0.f), w2, up);
        um = fmaf(fmaxf(-w, 0.f), w2, um);
    }
    upm[k] = up;
    upm[64 + k] = um;
    if (k == 0) {
        int z = 1;
        for (int c = 0; c < 32; ++c) if (sb[c] != 0.f) z = 0;
        *bzero = z;
    }
}

// global bucket histogram (LDS-staged; few global int atomics)
__global__ void k_hist(const int* __restrict__ e32, const int* __restrict__ flag,
                       int E, int NSB, int* __restrict__ gHist) {
    __shared__ int sh[NSBMAX];
    for (int i = threadIdx.x; i < NSB; i += TPB) sh[i] = 0;
    __syncthreads();
    int f = *flag;
    long stride = (long)gridDim.x * TPB;
    for (long e = (long)blockIdx.x * TPB + threadIdx.x; e < E; e += stride) {
        int d = e32[((long)E + e) << f];
        atomicAdd(&sh[d >> LBITS], 1);
    }
    __syncthreads();
    for (int i = threadIdx.x; i < NSB; i += TPB)
        if (sh[i]) atomicAdd(&gHist[i], sh[i]);
}

// one-block exclusive scan of NSB bucket counts -> base, cursor
__global__ void k_scan(const int* __restrict__ gHist, int NSB, int E,
                       int* __restrict__ base, int* __restrict__ cursor) {
    __shared__ int s[TPB];
    int K = (NSB + TPB - 1) / TPB;
    int t = threadIdx.x;
    int i0 = t * K;
    int tot = 0;
    for (int k = 0; k < K; ++k) { int i = i0 + k; if (i < NSB) tot += gHist[i]; }
    s[t] = tot;
    __syncthreads();
    for (int off = 1; off < TPB; off <<= 1) {
        int v = s[t];
        int u = (t >= off) ? s[t - off] : 0;
        __syncthreads();
        s[t] = v + u;
        __syncthreads();
    }
    int run = s[t] - tot;   // exclusive
    for (int k = 0; k < K; ++k) {
        int i = i0 + k;
        if (i < NSB) { int h = gHist[i]; base[i] = run; cursor[i] = run; run += h; }
    }
    if (t == 0) base[NSB] = E;
}

// partition edges bucket-major: per-chunk LDS hist -> one reservation atomic
// per (bucket,block) -> clustered scatter of packed (ldst<<24)|src.
// TPBP=1024 threads: 16 waves/CU to hide scatter latency.
__global__ void k_part(const int* __restrict__ e32, const int* __restrict__ flag,
                       int E, int NSB, int* __restrict__ cursor,
                       unsigned int* __restrict__ P, int chunk) {
    __shared__ int sh[NSBMAX];
    int c0 = blockIdx.x * chunk;
    int c1 = c0 + chunk; if (c1 > E) c1 = E;
    for (int i = threadIdx.x; i < NSB; i += TPBP) sh[i] = 0;
    __syncthreads();
    int f = *flag;
    for (int e = c0 + threadIdx.x; e < c1; e += TPBP) {
        int d = e32[((long)E + e) << f];
        atomicAdd(&sh[d >> LBITS], 1);
    }
    __syncthreads();
    for (int i = threadIdx.x; i < NSB; i += TPBP) {
        int c = sh[i];
        sh[i] = c ? atomicAdd(&cursor[i], c) : 0;   // LDS cell now holds cursor
    }
    __syncthreads();
    int sshift = 32 - LBITS;
    for (int e = c0 + threadIdx.x; e < c1; e += TPBP) {
        long ee = (long)e << f;
        int s = e32[ee];
        int d = e32[(((long)E) << f) + ee];
        int b = d >> LBITS;
        int pos = atomicAdd(&sh[b], 1);
        P[pos] = (unsigned)s | ((unsigned)(d & (SBSZ - 1)) << sshift);
    }
}

// per bucket: LDS degree histogram -> dinv, g
__global__ void k_deg(const unsigned int* __restrict__ P, const int* __restrict__ base,
                      int n, const float* __restrict__ feat,
                      float* __restrict__ dinv, float* __restrict__ g) {
    __shared__ int cnt[SBSZ];
    int b = blockIdx.x, t = threadIdx.x;
    cnt[t] = 0;
    __syncthreads();
    int p0 = base[b], p1 = base[b + 1];
    int sshift = 32 - LBITS;
    for (int p = p0 + t; p < p1; p += TPB)
        atomicAdd(&cnt[P[p] >> sshift], 1);
    __syncthreads();
    int v = (b << LBITS) + t;
    if (v < n) {
        float di = rsqrtf((float)(cnt[t] + 1));
        dinv[v] = di;
        g[v] = di * feat[v];
    }
}

// per bucket: A_v = g_v + sum g_src (LDS float adds) -> px, q±, pd
__global__ void k_aggA(const unsigned int* __restrict__ P, const int* __restrict__ base,
                       int n, const float* __restrict__ g,
                       const float* __restrict__ dinv, const int* __restrict__ bzero,
                       float2* __restrict__ q2, float2* __restrict__ pd,
                       float* __restrict__ Yagg) {
    __shared__ float A[SBSZ];
    int b = blockIdx.x, t = threadIdx.x;
    int v = (b << LBITS) + t;
    A[t] = (v < n) ? g[v] : 0.f;   // self term
    __syncthreads();
    int p0 = base[b], p1 = base[b + 1];
    int sshift = 32 - LBITS;
    unsigned smask = (1u << sshift) - 1;
    for (int p = p0 + t; p < p1; p += TPB) {
        unsigned e = P[p];
        atomicAdd(&A[e >> sshift], g[e & smask]);
    }
    __syncthreads();
    if (v < n) {
        float di = dinv[v];
        float px = di * A[t];
        pd[v] = make_float2(px, di);
        q2[v] = make_float2(di * fmaxf(px, 0.f), di * fmaxf(-px, 0.f));
        if (!*bzero) {
            float4* Y = (float4*)(Yagg + (size_t)v * 32);
#pragma unroll
            for (int i = 0; i < 8; ++i) Y[i] = make_float4(0.f, 0.f, 0.f, 0.f);
        }
    }
}

// per bucket (fast, b1==0): S± = q±_v + sum q±_src (LDS adds), then fused
// epilogue: out[v,k] = relu(dinv (S+ u+[k] + S- u-[k]) + b2[k]), coalesced.
__global__ void k_aggT(const unsigned int* __restrict__ P, const int* __restrict__ base,
                       int n, const float2* __restrict__ q2,
                       const float* __restrict__ dinv, const float* __restrict__ upm,
                       const float* __restrict__ b2, const int* __restrict__ bzero,
                       float* __restrict__ out) {
    if (!*bzero) return;
    __shared__ float Sp[SBSZ], Sm[SBSZ], Sd[SBSZ];
    __shared__ float su[192];    // u+ | u- | b2
    int b = blockIdx.x, t = threadIdx.x;
    int v0 = b << LBITS;
    int v = v0 + t;
    if (v < n) { float2 q = q2[v]; Sp[t] = q.x; Sm[t] = q.y; Sd[t] = dinv[v]; }
    else       { Sp[t] = 0.f; Sm[t] = 0.f; Sd[t] = 0.f; }
    if (t < 192) su[t] = (t < 128) ? upm[t] : b2[t - 128];
    __syncthreads();
    int p0 = base[b], p1 = base[b + 1];
    int sshift = 32 - LBITS;
    unsigned smask = (1u << sshift) - 1;
    for (int p = p0 + t; p < p1; p += TPB) {
        unsigned e = P[p];
        float2 q = q2[e & smask];
        int l = e >> sshift;
        atomicAdd(&Sp[l], q.x);
        atomicAdd(&Sm[l], q.y);
    }
    __syncthreads();
    int nv = n - v0; if (nv > SBSZ) nv = SBSZ; if (nv < 0) nv = 0;
    for (int o = t; o < nv * 64; o += TPB) {
        int vl = o >> 6, k = o & 63;
        float r = fmaf(Sd[vl], fmaf(Sp[vl], su[k], Sm[vl] * su[64 + k]), su[128 + k]);
        out[(size_t)(v0 + vl) * 64 + k] = fmaxf(r, 0.f);
    }
}

// ---- general-b1 fallback (flag-gated; never taken in this bench) ----
__global__ void k_aggY(const int* __restrict__ e32, const int* __restrict__ flag,
                       int E, const int* __restrict__ bzero,
                       const float2* __restrict__ pd,
                       const float* __restrict__ W1, const float* __restrict__ b1,
                       float* __restrict__ Yagg) {
    if (*bzero) return;
    __shared__ float sw[32], sb[32];
    if (threadIdx.x < 32) { sw[threadIdx.x] = W1[threadIdx.x]; sb[threadIdx.x] = b1[threadIdx.x]; }
    __syncthreads();
    int sh = *flag;
    long stride = (long)gridDim.x * TPB;
    for (long e = (long)blockIdx.x * TPB + threadIdx.x; e < E; e += stride) {
        int s = e32[e << sh];
        int d = e32[((long)E + e) << sh];
        float2 p = pd[s];
#pragma unroll
        for (int c = 0; c < 32; ++c) {
            float y = p.y * fmaxf(fmaf(sw[c], p.x, sb[c] * p.y), 0.f);
            atomicAdd(&Yagg[(size_t)d * 32 + c], y);
        }
    }
}

__global__ void k_final_gen(const float2* __restrict__ pd, const float* __restrict__ Yagg,
                            const float* __restrict__ W1, const float* __restrict__ b1,
                            const float* __restrict__ W2, const float* __restrict__ b2,
                            const int* __restrict__ bzero, int n, float* __restrict__ out) {
    if (*bzero) return;
    __shared__ float sW[32 * 64];
    __shared__ float sb2[64];
    __shared__ float sagg[8][33];
    int t = threadIdx.x;
    for (int i = t; i < 32 * 64; i += TPB) sW[i] = W2[i];
    if (t < 64) sb2[t] = b2[t];
    int vl = t >> 5, c = t & 31;
    int v = blockIdx.x * 8 + vl;
    float a = 0.f;
    if (v < n) {
        float2 p = pd[v];
        float dv = p.y;
        float yv = fmaxf(fmaf(W1[c], p.x, b1[c] * p.y), 0.f);
        a = dv * (dv * yv + Yagg[(size_t)v * 32 + c]);
    }
    __syncthreads();
    sagg[vl][c] = a;
    __syncthreads();
    if (v < n) {
        float o0 = sb2[c], o1 = sb2[c + 32];
#pragma unroll
        for (int j = 0; j < 32; ++j) {
            float x = sagg[vl][j];
            o0 += x * sW[j * 64 + c];
            o1 += x * sW[j * 64 + 32 + c];
        }
        out[(size_t)v * 64 + c]      = fmaxf(o0, 0.f);
        out[(size_t)v * 64 + 32 + c] = fmaxf(o1, 0.f);
    }
}

static inline size_t align256(size_t x) { return (x + 255) & ~(size_t)255; }

extern "C" void kernel_launch(void* const* d_in, const int* in_sizes, int n_in,
                              void* d_out, int out_size, void* d_ws, size_t ws_size,
                              hipStream_t stream) {
    const float* feat = (const float*)d_in[0];
    const int*   e32  = (const int*)d_in[1];
    const float* W1   = (const float*)d_in[2];
    const float* b1   = (const float*)d_in[3];
    const float* W2   = (const float*)d_in[4];
    const float* b2   = (const float*)d_in[5];
    float* out = (float*)d_out;

    int n = in_sizes[0];         // 100000
    int E = in_sizes[1] / 2;     // 3200000

    int NSB = (n + SBSZ - 1) >> LBITS;                    // 391 @ n=100K

    char* w = (char*)d_ws;
    size_t off = 0;
    auto alloc = [&](size_t bytes) -> char* { char* p = w + off; off = align256(off + bytes); return p; };
    unsigned int* P = (unsigned int*)alloc((size_t)E * 4);
    int*    gHist = (int*)alloc((size_t)NSB * 4);
    int*    base  = (int*)alloc((size_t)(NSB + 1) * 4);
    int*    cursor= (int*)alloc((size_t)NSB * 4);
    float*  dinv  = (float*)alloc((size_t)n * 4);
    float*  g     = (float*)alloc((size_t)n * 4);
    float2* q2    = (float2*)alloc((size_t)n * 8);
    float2* pd    = (float2*)alloc((size_t)n * 8);
    float*  upm   = (float*)alloc(128 * 4);
    int*    flag  = (int*)alloc(4);
    int*    bzero = (int*)alloc(4);
    float*  Yagg  = (float*)alloc((size_t)n * 32 * 4);    // general path only

    int chunk = (E + 255) / 256;          // 256 partition blocks
    int gC = (E + chunk - 1) / chunk;

    hipLaunchKernelGGL(k_detect,    dim3(1),    dim3(TPB),  0, stream, e32, E, flag, gHist, NSB);
    hipLaunchKernelGGL(k_uv,        dim3(1),    dim3(64),   0, stream, W1, b1, W2, upm, bzero);
    hipLaunchKernelGGL(k_hist,      dim3(256),  dim3(TPB),  0, stream, e32, flag, E, NSB, gHist);
    hipLaunchKernelGGL(k_scan,      dim3(1),    dim3(TPB),  0, stream, gHist, NSB, E, base, cursor);
    hipLaunchKernelGGL(k_part,      dim3(gC),   dim3(TPBP), 0, stream, e32, flag, E, NSB, cursor, P, chunk);
    hipLaunchKernelGGL(k_deg,       dim3(NSB),  dim3(TPB),  0, stream, P, base, n, feat, dinv, g);
    hipLaunchKernelGGL(k_aggA,      dim3(NSB),  dim3(TPB),  0, stream, P, base, n, g, dinv, bzero, q2, pd, Yagg);
    hipLaunchKernelGGL(k_aggT,      dim3(NSB),  dim3(TPB),  0, stream, P, base, n, q2, dinv, upm, b2, bzero, out);
    hipLaunchKernelGGL(k_aggY,      dim3(512),  dim3(TPB),  0, stream, e32, flag, E, bzero, pd, W1, b1, Yagg);
    hipLaunchKernelGGL(k_final_gen, dim3((n + 7) / 8), dim3(TPB), 0, stream, pd, Yagg, W1, b1, W2, b2, bzero, n, out);
}

// Round 7
// 133.391 us; speedup vs baseline: 4.8799x; 1.1284x over previous
//
#include <hip/hip_runtime.h>

// ---------------------------------------------------------------------------
// 2-layer GCN, symmetric norm + self loops — rank-2 scalarized, LDS-atomic
// segment sums over a coarse dst-bucket partition.
//
// feat is [n,1] and b1 == 0 (device-checked)  =>
//   px_v = dinv_v * (g_v + sum g_src),  g = dinv*feat
//   y[u,c] = w+_c relu(px_u) + w-_c relu(-px_u)         (rank-2, w± = max(±W1,0))
//   out[v,k] = relu( dinv_v (S+_v u+[k] + S-_v u-[k]) + b2[k] ),
//   S±_v = q±_v + sum q±_src,  q± = dinv relu(±px),  u± = w± @ W2 (2x64)
//
// R4 lesson: device-scope f32 atomics cost ~32B HBM writeback each -> all
// segment sums are LDS atomics inside dst-buckets.
// R5 lesson: partition scatter needs >=128B per-bucket runs + high wave count.
// R6 lesson: the bucket agg kernels ran at 13% occupancy (391 blocks x 4
// waves) and were gather-latency-bound -> TPB=1024 (16 waves/block) so
// ~24-32 waves/CU are resident to hide the random q2/g gathers.
// ---------------------------------------------------------------------------

#define TPB 256
#define TPBW 1024     // wide blocks: partition + bucket agg kernels
#define NSBMAX 1024   // max buckets (LDS hist arrays)
#define SBSZ 256      // nodes per bucket (= 1 << LBITS)
#define LBITS 8

// Detect int64 (low/high pairs) vs int32 edge layout (ids < 2^31 => int64
// high words are 0; sample odd 32-bit positions). Also zeroes gHist.
__global__ void k_detect(const int* __restrict__ e32, int E, int* __restrict__ flag,
                         int* __restrict__ gHist, int NSB) {
    __shared__ int ok;
    if (threadIdx.x == 0) ok = 1;
    __syncthreads();
    for (int i = threadIdx.x; i < NSB; i += TPB) gHist[i] = 0;
    int stride = E / 2048; if (stride < 1) stride = 1;
    bool bad = false;
#pragma unroll
    for (int i = 0; i < 8; ++i) {
        long k = (long)(threadIdx.x * 8 + i) * stride + 1;
        if (k < E && e32[2 * k + 1] != 0) bad = true;
    }
    if (bad) atomicAnd(&ok, 0);
    __syncthreads();
    if (threadIdx.x == 0) *flag = ok;   // 1 => int64 (shift 1), 0 => int32
}

// u±[k] = sum_c max(±W1[c],0) * W2[c,k]; bzero = all(b1==0). 1 block, 64 thr.
__global__ void k_uv(const float* __restrict__ W1, const float* __restrict__ b1,
                     const float* __restrict__ W2, float* __restrict__ upm,
                     int* __restrict__ bzero) {
    __shared__ float sw[32], sb[32];
    int k = threadIdx.x;
    if (k < 32) { sw[k] = W1[k]; sb[k] = b1[k]; }
    __syncthreads();
    float up = 0.f, um = 0.f;
#pragma unroll
    for (int c = 0; c < 32; ++c) {
        float w = sw[c];
        float w2 = W2[c * 64 + k];
        up = fmaf(fmaxf(w, 0.f), w2, up);
        um = fmaf(fmaxf(-w, 0.f), w2, um);
    }
    upm[k] = up;
    upm[64 + k] = um;
    if (k == 0) {
        int z = 1;
        for (int c = 0; c < 32; ++c) if (sb[c] != 0.f) z = 0;
        *bzero = z;
    }
}

// global bucket histogram (LDS-staged; few global int atomics)
__global__ void k_hist(const int* __restrict__ e32, const int* __restrict__ flag,
                       int E, int NSB, int* __restrict__ gHist) {
    __shared__ int sh[NSBMAX];
    for (int i = threadIdx.x; i < NSB; i += TPBW) sh[i] = 0;
    __syncthreads();
    int f = *flag;
    long stride = (long)gridDim.x * TPBW;
    for (long e = (long)blockIdx.x * TPBW + threadIdx.x; e < E; e += stride) {
        int d = e32[((long)E + e) << f];
        atomicAdd(&sh[d >> LBITS], 1);
    }
    __syncthreads();
    for (int i = threadIdx.x; i < NSB; i += TPBW)
        if (sh[i]) atomicAdd(&gHist[i], sh[i]);
}

// one-block exclusive scan of NSB bucket counts -> base, cursor
__global__ void k_scan(const int* __restrict__ gHist, int NSB, int E,
                       int* __restrict__ base, int* __restrict__ cursor) {
    __shared__ int s[TPB];
    int K = (NSB + TPB - 1) / TPB;
    int t = threadIdx.x;
    int i0 = t * K;
    int tot = 0;
    for (int k = 0; k < K; ++k) { int i = i0 + k; if (i < NSB) tot += gHist[i]; }
    s[t] = tot;
    __syncthreads();
    for (int off = 1; off < TPB; off <<= 1) {
        int v = s[t];
        int u = (t >= off) ? s[t - off] : 0;
        __syncthreads();
        s[t] = v + u;
        __syncthreads();
    }
    int run = s[t] - tot;   // exclusive
    for (int k = 0; k < K; ++k) {
        int i = i0 + k;
        if (i < NSB) { int h = gHist[i]; base[i] = run; cursor[i] = run; run += h; }
    }
    if (t == 0) base[NSB] = E;
}

// partition edges bucket-major: per-chunk LDS hist -> one reservation atomic
// per (bucket,block) -> clustered scatter of packed (ldst<<24)|src.
__global__ void k_part(const int* __restrict__ e32, const int* __restrict__ flag,
                       int E, int NSB, int* __restrict__ cursor,
                       unsigned int* __restrict__ P, int chunk) {
    __shared__ int sh[NSBMAX];
    int c0 = blockIdx.x * chunk;
    int c1 = c0 + chunk; if (c1 > E) c1 = E;
    for (int i = threadIdx.x; i < NSB; i += TPBW) sh[i] = 0;
    __syncthreads();
    int f = *flag;
    for (int e = c0 + threadIdx.x; e < c1; e += TPBW) {
        int d = e32[((long)E + e) << f];
        atomicAdd(&sh[d >> LBITS], 1);
    }
    __syncthreads();
    for (int i = threadIdx.x; i < NSB; i += TPBW) {
        int c = sh[i];
        sh[i] = c ? atomicAdd(&cursor[i], c) : 0;   // LDS cell now holds cursor
    }
    __syncthreads();
    int sshift = 32 - LBITS;
    for (int e = c0 + threadIdx.x; e < c1; e += TPBW) {
        long ee = (long)e << f;
        int s = e32[ee];
        int d = e32[(((long)E) << f) + ee];
        int b = d >> LBITS;
        int pos = atomicAdd(&sh[b], 1);
        P[pos] = (unsigned)s | ((unsigned)(d & (SBSZ - 1)) << sshift);
    }
}

// per bucket (wide block): LDS degree histogram -> dinv, g
__global__ void k_deg(const unsigned int* __restrict__ P, const int* __restrict__ base,
                      int n, const float* __restrict__ feat,
                      float* __restrict__ dinv, float* __restrict__ g) {
    __shared__ int cnt[SBSZ];
    int b = blockIdx.x, t = threadIdx.x;
    if (t < SBSZ) cnt[t] = 0;
    __syncthreads();
    int p0 = base[b], p1 = base[b + 1];
    int sshift = 32 - LBITS;
    for (int p = p0 + t; p < p1; p += TPBW)
        atomicAdd(&cnt[P[p] >> sshift], 1);
    __syncthreads();
    int v = (b << LBITS) + t;
    if (t < SBSZ && v < n) {
        float di = rsqrtf((float)(cnt[t] + 1));
        dinv[v] = di;
        g[v] = di * feat[v];
    }
}

// per bucket (wide block): A_v = g_v + sum g_src (LDS float adds) -> px, q±
__global__ void k_aggA(const unsigned int* __restrict__ P, const int* __restrict__ base,
                       int n, const float* __restrict__ g,
                       const float* __restrict__ dinv, const int* __restrict__ bzero,
                       float2* __restrict__ q2, float2* __restrict__ pd,
                       float* __restrict__ Yagg) {
    __shared__ float A[SBSZ];
    int b = blockIdx.x, t = threadIdx.x;
    int v = (b << LBITS) + t;
    if (t < SBSZ) A[t] = (v < n) ? g[v] : 0.f;   // self term
    __syncthreads();
    int p0 = base[b], p1 = base[b + 1];
    int sshift = 32 - LBITS;
    unsigned smask = (1u << sshift) - 1;
    for (int p = p0 + t; p < p1; p += TPBW) {
        unsigned e = P[p];
        atomicAdd(&A[e >> sshift], g[e & smask]);
    }
    __syncthreads();
    if (t < SBSZ && v < n) {
        float di = dinv[v];
        float px = di * A[t];
        q2[v] = make_float2(di * fmaxf(px, 0.f), di * fmaxf(-px, 0.f));
        if (!*bzero) {                          // fallback-only data
            pd[v] = make_float2(px, di);
            float4* Y = (float4*)(Yagg + (size_t)v * 32);
#pragma unroll
            for (int i = 0; i < 8; ++i) Y[i] = make_float4(0.f, 0.f, 0.f, 0.f);
        }
    }
}

// per bucket (wide block, fast, b1==0): S± = q±_v + sum q±_src (LDS adds),
// then fused epilogue: out[v,k] = relu(dinv (S+ u+[k] + S- u-[k]) + b2[k]).
__global__ void k_aggT(const unsigned int* __restrict__ P, const int* __restrict__ base,
                       int n, const float2* __restrict__ q2,
                       const float* __restrict__ dinv, const float* __restrict__ upm,
                       const float* __restrict__ b2, const int* __restrict__ bzero,
                       float* __restrict__ out) {
    if (!*bzero) return;
    __shared__ float Sp[SBSZ], Sm[SBSZ], Sd[SBSZ];
    __shared__ float su[192];    // u+ | u- | b2
    int b = blockIdx.x, t = threadIdx.x;
    int v0 = b << LBITS;
    int v = v0 + t;
    if (t < SBSZ) {
        if (v < n) { float2 q = q2[v]; Sp[t] = q.x; Sm[t] = q.y; Sd[t] = dinv[v]; }
        else       { Sp[t] = 0.f; Sm[t] = 0.f; Sd[t] = 0.f; }
    }
    if (t < 192) su[t] = (t < 128) ? upm[t] : b2[t - 128];
    __syncthreads();
    int p0 = base[b], p1 = base[b + 1];
    int sshift = 32 - LBITS;
    unsigned smask = (1u << sshift) - 1;
    for (int p = p0 + t; p < p1; p += TPBW) {
        unsigned e = P[p];
        float2 q = q2[e & smask];
        int l = e >> sshift;
        atomicAdd(&Sp[l], q.x);
        atomicAdd(&Sm[l], q.y);
    }
    __syncthreads();
    int nv = n - v0; if (nv > SBSZ) nv = SBSZ; if (nv < 0) nv = 0;
    for (int o = t; o < nv * 64; o += TPBW) {
        int vl = o >> 6, k = o & 63;
        float r = fmaf(Sd[vl], fmaf(Sp[vl], su[k], Sm[vl] * su[64 + k]), su[128 + k]);
        out[(size_t)(v0 + vl) * 64 + k] = fmaxf(r, 0.f);
    }
}

// ---- general-b1 fallback (flag-gated; never taken in this bench) ----
__global__ void k_aggY(const int* __restrict__ e32, const int* __restrict__ flag,
                       int E, const int* __restrict__ bzero,
                       const float2* __restrict__ pd,
                       const float* __restrict__ W1, const float* __restrict__ b1,
                       float* __restrict__ Yagg) {
    if (*bzero) return;
    __shared__ float sw[32], sb[32];
    if (threadIdx.x < 32) { sw[threadIdx.x] = W1[threadIdx.x]; sb[threadIdx.x] = b1[threadIdx.x]; }
    __syncthreads();
    int sh = *flag;
    long stride = (long)gridDim.x * TPB;
    for (long e = (long)blockIdx.x * TPB + threadIdx.x; e < E; e += stride) {
        int s = e32[e << sh];
        int d = e32[((long)E + e) << sh];
        float2 p = pd[s];
#pragma unroll
        for (int c = 0; c < 32; ++c) {
            float y = p.y * fmaxf(fmaf(sw[c], p.x, sb[c] * p.y), 0.f);
            atomicAdd(&Yagg[(size_t)d * 32 + c], y);
        }
    }
}

__global__ void k_final_gen(const float2* __restrict__ pd, const float* __restrict__ Yagg,
                            const float* __restrict__ W1, const float* __restrict__ b1,
                            const float* __restrict__ W2, const float* __restrict__ b2,
                            const int* __restrict__ bzero, int n, float* __restrict__ out) {
    if (*bzero) return;
    __shared__ float sW[32 * 64];
    __shared__ float sb2[64];
    __shared__ float sagg[8][33];
    int t = threadIdx.x;
    for (int i = t; i < 32 * 64; i += TPB) sW[i] = W2[i];
    if (t < 64) sb2[t] = b2[t];
    int vl = t >> 5, c = t & 31;
    int nblk = (n + 7) / 8;
    for (int blk = blockIdx.x; blk < nblk; blk += gridDim.x) {
        int v = blk * 8 + vl;
        float a = 0.f;
        if (v < n) {
            float2 p = pd[v];
            float dv = p.y;
            float yv = fmaxf(fmaf(W1[c], p.x, b1[c] * p.y), 0.f);
            a = dv * (dv * yv + Yagg[(size_t)v * 32 + c]);
        }
        __syncthreads();
        sagg[vl][c] = a;
        __syncthreads();
        if (v < n) {
            float o0 = sb2[c], o1 = sb2[c + 32];
#pragma unroll
            for (int j = 0; j < 32; ++j) {
                float x = sagg[vl][j];
                o0 += x * sW[j * 64 + c];
                o1 += x * sW[j * 64 + 32 + c];
            }
            out[(size_t)v * 64 + c]      = fmaxf(o0, 0.f);
            out[(size_t)v * 64 + 32 + c] = fmaxf(o1, 0.f);
        }
    }
}

static inline size_t align256(size_t x) { return (x + 255) & ~(size_t)255; }

extern "C" void kernel_launch(void* const* d_in, const int* in_sizes, int n_in,
                              void* d_out, int out_size, void* d_ws, size_t ws_size,
                              hipStream_t stream) {
    const float* feat = (const float*)d_in[0];
    const int*   e32  = (const int*)d_in[1];
    const float* W1   = (const float*)d_in[2];
    const float* b1   = (const float*)d_in[3];
    const float* W2   = (const float*)d_in[4];
    const float* b2   = (const float*)d_in[5];
    float* out = (float*)d_out;

    int n = in_sizes[0];         // 100000
    int E = in_sizes[1] / 2;     // 3200000

    int NSB = (n + SBSZ - 1) >> LBITS;                    // 391 @ n=100K

    char* w = (char*)d_ws;
    size_t off = 0;
    auto alloc = [&](size_t bytes) -> char* { char* p = w + off; off = align256(off + bytes); return p; };
    unsigned int* P = (unsigned int*)alloc((size_t)E * 4);
    int*    gHist = (int*)alloc((size_t)NSB * 4);
    int*    base  = (int*)alloc((size_t)(NSB + 1) * 4);
    int*    cursor= (int*)alloc((size_t)NSB * 4);
    float*  dinv  = (float*)alloc((size_t)n * 4);
    float*  g     = (float*)alloc((size_t)n * 4);
    float2* q2    = (float2*)alloc((size_t)n * 8);
    float2* pd    = (float2*)alloc((size_t)n * 8);
    float*  upm   = (float*)alloc(128 * 4);
    int*    flag  = (int*)alloc(4);
    int*    bzero = (int*)alloc(4);
    float*  Yagg  = (float*)alloc((size_t)n * 32 * 4);    // general path only

    int chunk = (E + 255) / 256;          // 256 partition blocks
    int gC = (E + chunk - 1) / chunk;

    hipLaunchKernelGGL(k_detect,    dim3(1),    dim3(TPB),  0, stream, e32, E, flag, gHist, NSB);
    hipLaunchKernelGGL(k_uv,        dim3(1),    dim3(64),   0, stream, W1, b1, W2, upm, bzero);
    hipLaunchKernelGGL(k_hist,      dim3(128),  dim3(TPBW), 0, stream, e32, flag, E, NSB, gHist);
    hipLaunchKernelGGL(k_scan,      dim3(1),    dim3(TPB),  0, stream, gHist, NSB, E, base, cursor);
    hipLaunchKernelGGL(k_part,      dim3(gC),   dim3(TPBW), 0, stream, e32, flag, E, NSB, cursor, P, chunk);
    hipLaunchKernelGGL(k_deg,       dim3(NSB),  dim3(TPBW), 0, stream, P, base, n, feat, dinv, g);
    hipLaunchKernelGGL(k_aggA,      dim3(NSB),  dim3(TPBW), 0, stream, P, base, n, g, dinv, bzero, q2, pd, Yagg);
    hipLaunchKernelGGL(k_aggT,      dim3(NSB),  dim3(TPBW), 0, stream, P, base, n, q2, dinv, upm, b2, bzero, out);
    hipLaunchKernelGGL(k_aggY,      dim3(512),  dim3(TPB),  0, stream, e32, flag, E, bzero, pd, W1, b1, Yagg);
    hipLaunchKernelGGL(k_final_gen, dim3(1024), dim3(TPB),  0, stream, pd, Yagg, W1, b1, W2, b2, bzero, n, out);
}

// Round 8
// 130.726 us; speedup vs baseline: 4.9795x; 1.0204x over previous
//
#include <hip/hip_runtime.h>

// ---------------------------------------------------------------------------
// 2-layer GCN, symmetric norm + self loops — rank-2 scalarized, LDS-atomic
// segment sums over a dst-bucket partition, SPLIT sub-blocks per bucket.
//
// feat is [n,1] and b1 == 0 (device-checked)  =>
//   px_v = dinv_v * (g_v + sum g_src),  g = dinv*feat
//   qs_v = dinv_v * px_v   (signed; q± = relu(±qs) and only one is nonzero)
//   out[v,k] = relu( dinv_v (S+_v u+[k] + S-_v u-[k]) + b2[k] ),
//   S±_v = relu(±qs_v) + sum relu(±qs_src),  u± = max(±W1,0) @ W2 (2x64)
//
// R4: global f32 atomics ~32B HBM writeback each -> never use per-edge.
// R5: partition scatter needs >=128B per-bucket runs + many waves.
// R6: bucket agg kernels need high occupancy for gather latency.
// R7: k_aggT time invariant under 4x occupancy, VALU/HBM idle -> per-CU LDS
//     atomic pipe saturated (2 atomics/edge). Fix: 1 atomic/edge (sign trick)
//     + SPLIT=4 sub-bucket blocks with private LDS accs merged via PLAIN
//     coalesced partial stores (no atomics) + node-parallel reduce/epilogue.
// ---------------------------------------------------------------------------

#define TPB 256
#define TPBW 1024     // wide blocks: hist + partition
#define NSBMAX 1024   // max buckets (LDS hist arrays)
#define SBSZ 256      // nodes per bucket (= 1 << LBITS)
#define LBITS 8
#define SPLIT 4       // sub-blocks per bucket in agg kernels

// Detect int64 (low/high pairs) vs int32 edge layout (ids < 2^31 => int64
// high words are 0; sample odd 32-bit positions). Also zeroes gHist.
__global__ void k_detect(const int* __restrict__ e32, int E, int* __restrict__ flag,
                         int* __restrict__ gHist, int NSB) {
    __shared__ int ok;
    if (threadIdx.x == 0) ok = 1;
    __syncthreads();
    for (int i = threadIdx.x; i < NSB; i += TPB) gHist[i] = 0;
    int stride = E / 2048; if (stride < 1) stride = 1;
    bool bad = false;
#pragma unroll
    for (int i = 0; i < 8; ++i) {
        long k = (long)(threadIdx.x * 8 + i) * stride + 1;
        if (k < E && e32[2 * k + 1] != 0) bad = true;
    }
    if (bad) atomicAnd(&ok, 0);
    __syncthreads();
    if (threadIdx.x == 0) *flag = ok;   // 1 => int64 (shift 1), 0 => int32
}

// u±[k] = sum_c max(±W1[c],0) * W2[c,k]; bzero = all(b1==0). 1 block, 64 thr.
__global__ void k_uv(const float* __restrict__ W1, const float* __restrict__ b1,
                     const float* __restrict__ W2, float* __restrict__ upm,
                     int* __restrict__ bzero) {
    __shared__ float sw[32], sb[32];
    int k = threadIdx.x;
    if (k < 32) { sw[k] = W1[k]; sb[k] = b1[k]; }
    __syncthreads();
    float up = 0.f, um = 0.f;
#pragma unroll
    for (int c = 0; c < 32; ++c) {
        float w = sw[c];
        float w2 = W2[c * 64 + k];
        up = fmaf(fmaxf(w, 0.f), w2, up);
        um = fmaf(fmaxf(-w, 0.f), w2, um);
    }
    upm[k] = up;
    upm[64 + k] = um;
    if (k == 0) {
        int z = 1;
        for (int c = 0; c < 32; ++c) if (sb[c] != 0.f) z = 0;
        *bzero = z;
    }
}

// global bucket histogram (LDS-staged; few global int atomics)
__global__ void k_hist(const int* __restrict__ e32, const int* __restrict__ flag,
                       int E, int NSB, int* __restrict__ gHist) {
    __shared__ int sh[NSBMAX];
    for (int i = threadIdx.x; i < NSB; i += TPBW) sh[i] = 0;
    __syncthreads();
    int f = *flag;
    long stride = (long)gridDim.x * TPBW;
    for (long e = (long)blockIdx.x * TPBW + threadIdx.x; e < E; e += stride) {
        int d = e32[((long)E + e) << f];
        atomicAdd(&sh[d >> LBITS], 1);
    }
    __syncthreads();
    for (int i = threadIdx.x; i < NSB; i += TPBW)
        if (sh[i]) atomicAdd(&gHist[i], sh[i]);
}

// one-block exclusive scan of NSB bucket counts -> base, cursor
__global__ void k_scan(const int* __restrict__ gHist, int NSB, int E,
                       int* __restrict__ base, int* __restrict__ cursor) {
    __shared__ int s[TPB];
    int K = (NSB + TPB - 1) / TPB;
    int t = threadIdx.x;
    int i0 = t * K;
    int tot = 0;
    for (int k = 0; k < K; ++k) { int i = i0 + k; if (i < NSB) tot += gHist[i]; }
    s[t] = tot;
    __syncthreads();
    for (int off = 1; off < TPB; off <<= 1) {
        int v = s[t];
        int u = (t >= off) ? s[t - off] : 0;
        __syncthreads();
        s[t] = v + u;
        __syncthreads();
    }
    int run = s[t] - tot;   // exclusive
    for (int k = 0; k < K; ++k) {
        int i = i0 + k;
        if (i < NSB) { int h = gHist[i]; base[i] = run; cursor[i] = run; run += h; }
    }
    if (t == 0) base[NSB] = E;
}

// partition edges bucket-major: per-chunk LDS hist -> one reservation atomic
// per (bucket,block) -> clustered scatter of packed (ldst<<24)|src.
__global__ void k_part(const int* __restrict__ e32, const int* __restrict__ flag,
                       int E, int NSB, int* __restrict__ cursor,
                       unsigned int* __restrict__ P, int chunk) {
    __shared__ int sh[NSBMAX];
    int c0 = blockIdx.x * chunk;
    int c1 = c0 + chunk; if (c1 > E) c1 = E;
    for (int i = threadIdx.x; i < NSB; i += TPBW) sh[i] = 0;
    __syncthreads();
    int f = *flag;
    for (int e = c0 + threadIdx.x; e < c1; e += TPBW) {
        int d = e32[((long)E + e) << f];
        atomicAdd(&sh[d >> LBITS], 1);
    }
    __syncthreads();
    for (int i = threadIdx.x; i < NSB; i += TPBW) {
        int c = sh[i];
        sh[i] = c ? atomicAdd(&cursor[i], c) : 0;   // LDS cell now holds cursor
    }
    __syncthreads();
    int sshift = 32 - LBITS;
    for (int e = c0 + threadIdx.x; e < c1; e += TPBW) {
        long ee = (long)e << f;
        int s = e32[ee];
        int d = e32[(((long)E) << f) + ee];
        int b = d >> LBITS;
        int pos = atomicAdd(&sh[b], 1);
        P[pos] = (unsigned)s | ((unsigned)(d & (SBSZ - 1)) << sshift);
    }
}

// per (bucket, quarter): LDS degree histogram -> plain partial store
__global__ void k_degS(const unsigned int* __restrict__ P, const int* __restrict__ base,
                       int n, int* __restrict__ cntP) {
    __shared__ int cnt[SBSZ];
    int bb = blockIdx.x / SPLIT, pp = blockIdx.x % SPLIT;
    int t = threadIdx.x;
    cnt[t] = 0;
    __syncthreads();
    int p0 = base[bb], len = base[bb + 1] - p0;
    int s0 = p0 + (int)((long)len * pp / SPLIT);
    int s1 = p0 + (int)((long)len * (pp + 1) / SPLIT);
    int sshift = 32 - LBITS;
    for (int p = s0 + t; p < s1; p += TPB)
        atomicAdd(&cnt[P[p] >> sshift], 1);
    __syncthreads();
    int v = (bb << LBITS) + t;
    if (v < n) cntP[pp * n + v] = cnt[t];
}

// node-parallel: cnt = sum partials -> dinv, g
__global__ void k_prep1(const int* __restrict__ cntP, const float* __restrict__ feat,
                        int n, float* __restrict__ dinv, float* __restrict__ g) {
    int v = blockIdx.x * TPB + threadIdx.x;
    if (v >= n) return;
    int c = 0;
#pragma unroll
    for (int pp = 0; pp < SPLIT; ++pp) c += cntP[pp * n + v];
    float di = rsqrtf((float)(c + 1));
    dinv[v] = di;
    g[v] = di * feat[v];
}

// per (bucket, quarter): partial A sums (LDS f32 atomics, 1/edge)
__global__ void k_aggAS(const unsigned int* __restrict__ P, const int* __restrict__ base,
                        int n, const float* __restrict__ g, float* __restrict__ AP) {
    __shared__ float A[SBSZ];
    int bb = blockIdx.x / SPLIT, pp = blockIdx.x % SPLIT;
    int t = threadIdx.x;
    A[t] = 0.f;
    __syncthreads();
    int p0 = base[bb], len = base[bb + 1] - p0;
    int s0 = p0 + (int)((long)len * pp / SPLIT);
    int s1 = p0 + (int)((long)len * (pp + 1) / SPLIT);
    int sshift = 32 - LBITS;
    unsigned smask = (1u << sshift) - 1;
    for (int p = s0 + t; p < s1; p += TPB) {
        unsigned e = P[p];
        atomicAdd(&A[e >> sshift], g[e & smask]);
    }
    __syncthreads();
    int v = (bb << LBITS) + t;
    if (v < n) AP[pp * n + v] = A[t];
}

// node-parallel: A = g_v + sum partials -> px -> signed qs = dinv*px; pd (fallback)
__global__ void k_prep2(const float* __restrict__ AP, const float* __restrict__ g,
                        const float* __restrict__ dinv, int n, const int* __restrict__ bzero,
                        float* __restrict__ qs, float2* __restrict__ pd,
                        float* __restrict__ Yagg) {
    int v = blockIdx.x * TPB + threadIdx.x;
    if (v >= n) return;
    float A = g[v];
#pragma unroll
    for (int pp = 0; pp < SPLIT; ++pp) A += AP[pp * n + v];
    float di = dinv[v];
    float px = di * A;
    qs[v] = di * px;
    if (!*bzero) {
        pd[v] = make_float2(px, di);
        float4* Y = (float4*)(Yagg + (size_t)v * 32);
#pragma unroll
        for (int i = 0; i < 8; ++i) Y[i] = make_float4(0.f, 0.f, 0.f, 0.f);
    }
}

// per (bucket, quarter): S± partials. ONE LDS atomic per edge (sign trick):
// only one of relu(±qs) is nonzero -> predicated address, |qs| value.
__global__ void k_aggTS(const unsigned int* __restrict__ P, const int* __restrict__ base,
                        int n, const float* __restrict__ qs, float2* __restrict__ SP2) {
    __shared__ float Sp[SBSZ], Sm[SBSZ];
    int bb = blockIdx.x / SPLIT, pp = blockIdx.x % SPLIT;
    int t = threadIdx.x;
    Sp[t] = 0.f; Sm[t] = 0.f;
    __syncthreads();
    int p0 = base[bb], len = base[bb + 1] - p0;
    int s0 = p0 + (int)((long)len * pp / SPLIT);
    int s1 = p0 + (int)((long)len * (pp + 1) / SPLIT);
    int sshift = 32 - LBITS;
    unsigned smask = (1u << sshift) - 1;
    for (int p = s0 + t; p < s1; p += TPB) {
        unsigned e = P[p];
        float q = qs[e & smask];
        int l = e >> sshift;
        float* addr = (q >= 0.f) ? &Sp[l] : &Sm[l];
        atomicAdd(addr, fabsf(q));
    }
    __syncthreads();
    int v = (bb << LBITS) + t;
    if (v < n) SP2[pp * n + v] = make_float2(Sp[t], Sm[t]);
}

// epilogue (fast, b1==0): thread per (v,k); S± = relu(±qs_v) + sum partials;
// out[v,k] = relu(dinv (S+ u+[k] + S- u-[k]) + b2[k]). Pure coalesced write.
__global__ void k_out(const float* __restrict__ qs, const float* __restrict__ dinv,
                      const float2* __restrict__ SP2, const float* __restrict__ upm,
                      const float* __restrict__ b2, const int* __restrict__ bzero,
                      int n, float* __restrict__ out) {
    if (!*bzero) return;
    __shared__ float su[192];    // u+ | u- | b2
    if (threadIdx.x < 192) su[threadIdx.x] = (threadIdx.x < 128) ? upm[threadIdx.x] : b2[threadIdx.x - 128];
    __syncthreads();
    int o = blockIdx.x * TPB + threadIdx.x;
    if (o >= n * 64) return;
    int v = o >> 6, k = o & 63;
    float qv = qs[v];
    float Sp = fmaxf(qv, 0.f), Sm = fmaxf(-qv, 0.f);
#pragma unroll
    for (int pp = 0; pp < SPLIT; ++pp) { float2 s = SP2[pp * n + v]; Sp += s.x; Sm += s.y; }
    float r = fmaf(dinv[v], fmaf(Sp, su[k], Sm * su[64 + k]), su[128 + k]);
    out[o] = fmaxf(r, 0.f);
}

// ---- general-b1 fallback (flag-gated; never taken in this bench) ----
__global__ void k_aggY(const int* __restrict__ e32, const int* __restrict__ flag,
                       int E, const int* __restrict__ bzero,
                       const float2* __restrict__ pd,
                       const float* __restrict__ W1, const float* __restrict__ b1,
                       float* __restrict__ Yagg) {
    if (*bzero) return;
    __shared__ float sw[32], sb[32];
    if (threadIdx.x < 32) { sw[threadIdx.x] = W1[threadIdx.x]; sb[threadIdx.x] = b1[threadIdx.x]; }
    __syncthreads();
    int sh = *flag;
    long stride = (long)gridDim.x * TPB;
    for (long e = (long)blockIdx.x * TPB + threadIdx.x; e < E; e += stride) {
        int s = e32[e << sh];
        int d = e32[((long)E + e) << sh];
        float2 p = pd[s];
#pragma unroll
        for (int c = 0; c < 32; ++c) {
            float y = p.y * fmaxf(fmaf(sw[c], p.x, sb[c] * p.y), 0.f);
            atomicAdd(&Yagg[(size_t)d * 32 + c], y);
        }
    }
}

__global__ void k_final_gen(const float2* __restrict__ pd, const float* __restrict__ Yagg,
                            const float* __restrict__ W1, const float* __restrict__ b1,
                            const float* __restrict__ W2, const float* __restrict__ b2,
                            const int* __restrict__ bzero, int n, float* __restrict__ out) {
    if (*bzero) return;
    __shared__ float sW[32 * 64];
    __shared__ float sb2[64];
    __shared__ float sagg[8][33];
    int t = threadIdx.x;
    for (int i = t; i < 32 * 64; i += TPB) sW[i] = W2[i];
    if (t < 64) sb2[t] = b2[t];
    int vl = t >> 5, c = t & 31;
    int nblk = (n + 7) / 8;
    for (int blk = blockIdx.x; blk < nblk; blk += gridDim.x) {
        int v = blk * 8 + vl;
        float a = 0.f;
        if (v < n) {
            float2 p = pd[v];
            float dv = p.y;
            float yv = fmaxf(fmaf(W1[c], p.x, b1[c] * p.y), 0.f);
            a = dv * (dv * yv + Yagg[(size_t)v * 32 + c]);
        }
        __syncthreads();
        sagg[vl][c] = a;
        __syncthreads();
        if (v < n) {
            float o0 = sb2[c], o1 = sb2[c + 32];
#pragma unroll
            for (int j = 0; j < 32; ++j) {
                float x = sagg[vl][j];
                o0 += x * sW[j * 64 + c];
                o1 += x * sW[j * 64 + 32 + c];
            }
            out[(size_t)v * 64 + c]      = fmaxf(o0, 0.f);
            out[(size_t)v * 64 + 32 + c] = fmaxf(o1, 0.f);
        }
    }
}

static inline size_t align256(size_t x) { return (x + 255) & ~(size_t)255; }

extern "C" void kernel_launch(void* const* d_in, const int* in_sizes, int n_in,
                              void* d_out, int out_size, void* d_ws, size_t ws_size,
                              hipStream_t stream) {
    const float* feat = (const float*)d_in[0];
    const int*   e32  = (const int*)d_in[1];
    const float* W1   = (const float*)d_in[2];
    const float* b1   = (const float*)d_in[3];
    const float* W2   = (const float*)d_in[4];
    const float* b2   = (const float*)d_in[5];
    float* out = (float*)d_out;

    int n = in_sizes[0];         // 100000
    int E = in_sizes[1] / 2;     // 3200000

    int NSB = (n + SBSZ - 1) >> LBITS;                    // 391 @ n=100K

    char* w = (char*)d_ws;
    size_t off = 0;
    auto alloc = [&](size_t bytes) -> char* { char* p = w + off; off = align256(off + bytes); return p; };
    unsigned int* P = (unsigned int*)alloc((size_t)E * 4);
    int*    gHist = (int*)alloc((size_t)NSB * 4);
    int*    base  = (int*)alloc((size_t)(NSB + 1) * 4);
    int*    cursor= (int*)alloc((size_t)NSB * 4);
    int*    cntP  = (int*)alloc((size_t)SPLIT * n * 4);
    float*  AP    = (float*)alloc((size_t)SPLIT * n * 4);
    float2* SP2   = (float2*)alloc((size_t)SPLIT * n * 8);
    float*  dinv  = (float*)alloc((size_t)n * 4);
    float*  g     = (float*)alloc((size_t)n * 4);
    float*  qs    = (float*)alloc((size_t)n * 4);
    float2* pd    = (float2*)alloc((size_t)n * 8);
    float*  upm   = (float*)alloc(128 * 4);
    int*    flag  = (int*)alloc(4);
    int*    bzero = (int*)alloc(4);
    float*  Yagg  = (float*)alloc((size_t)n * 32 * 4);    // general path only

    int chunk = (E + 255) / 256;          // 256 partition blocks
    int gC = (E + chunk - 1) / chunk;
    int gN = (n + TPB - 1) / TPB;
    int gS = NSB * SPLIT;
    int gO = (n * 64 + TPB - 1) / TPB;

    hipLaunchKernelGGL(k_detect,    dim3(1),    dim3(TPB),  0, stream, e32, E, flag, gHist, NSB);
    hipLaunchKernelGGL(k_uv,        dim3(1),    dim3(64),   0, stream, W1, b1, W2, upm, bzero);
    hipLaunchKernelGGL(k_hist,      dim3(256),  dim3(TPBW), 0, stream, e32, flag, E, NSB, gHist);
    hipLaunchKernelGGL(k_scan,      dim3(1),    dim3(TPB),  0, stream, gHist, NSB, E, base, cursor);
    hipLaunchKernelGGL(k_part,      dim3(gC),   dim3(TPBW), 0, stream, e32, flag, E, NSB, cursor, P, chunk);
    hipLaunchKernelGGL(k_degS,      dim3(gS),   dim3(TPB),  0, stream, P, base, n, cntP);
    hipLaunchKernelGGL(k_prep1,     dim3(gN),   dim3(TPB),  0, stream, cntP, feat, n, dinv, g);
    hipLaunchKernelGGL(k_aggAS,     dim3(gS),   dim3(TPB),  0, stream, P, base, n, g, AP);
    hipLaunchKernelGGL(k_prep2,     dim3(gN),   dim3(TPB),  0, stream, AP, g, dinv, n, bzero, qs, pd, Yagg);
    hipLaunchKernelGGL(k_aggTS,     dim3(gS),   dim3(TPB),  0, stream, P, base, n, qs, SP2);
    hipLaunchKernelGGL(k_out,       dim3(gO),   dim3(TPB),  0, stream, qs, dinv, SP2, upm, b2, bzero, n, out);
    hipLaunchKernelGGL(k_aggY,      dim3(512),  dim3(TPB),  0, stream, e32, flag, E, bzero, pd, W1, b1, Yagg);
    hipLaunchKernelGGL(k_final_gen, dim3(1024), dim3(TPB),  0, stream, pd, Yagg, W1, b1, W2, b2, bzero, n, out);
}

// Round 9
// 122.355 us; speedup vs baseline: 5.3201x; 1.0684x over previous
//
#include <hip/hip_runtime.h>

// ---------------------------------------------------------------------------
// 2-layer GCN, symmetric norm + self loops — rank-2 scalarized, LDS-atomic
// segment sums over a dst-bucket partition, SPLIT sub-blocks per bucket.
//
// feat is [n,1] and b1 == 0 (device-checked)  =>
//   px_v = dinv_v * (g_v + sum g_src),  g = dinv*feat
//   qs_v = dinv_v * px_v   (signed; q± = relu(±qs) and only one is nonzero)
//   out[v,k] = relu( dinv_v (S+_v u+[k] + S-_v u-[k]) + b2[k] ),
//   S±_v = relu(±qs_v) + sum relu(±qs_src),  u± = max(±W1,0) @ W2 (2x64)
//
// R4: global f32 atomics ~32B HBM writeback each -> never use per-edge.
// R5: partition scatter needs >=128B per-bucket runs + many waves.
// R6: bucket agg kernels need high occupancy for gather latency.
// R7: per-CU LDS atomic pipe saturates (~4-5cy/lane-op); cut atomics/edge.
// R8: k_part was the last 2-atomic/edge kernel (per-chunk hist + cursor).
//     Fix: keep the FULL 2D histogram H[chunk][bucket] from k_hist2, column-
//     scan it into exact per-(chunk,bucket) offsets -> k_part2 needs only the
//     local cursor bump (1 LDS atomic/edge), no reservation atomics at all.
// ---------------------------------------------------------------------------

#define TPB 256
#define TPBW 1024     // wide blocks: hist + partition
#define NSBMAX 1024   // max buckets (LDS arrays)
#define SBSZ 256      // nodes per bucket (= 1 << LBITS)
#define LBITS 8
#define SPLIT 4       // sub-blocks per bucket in agg kernels
#define NCHUNK 256    // edge chunks (= partition/hist grid)

// Fused: edge-layout detect (int64 low/high pairs vs int32; ids < 2^31 so
// int64 high words are 0 — sample odd 32-bit positions)  +  u± = max(±W1,0)@W2
// + bzero = all(b1==0). One block, 256 threads.
__global__ void k_init(const int* __restrict__ e32, int E, int* __restrict__ flag,
                       const float* __restrict__ W1, const float* __restrict__ b1,
                       const float* __restrict__ W2, float* __restrict__ upm,
                       int* __restrict__ bzero) {
    __shared__ int ok;
    __shared__ float sw[32], sb[32];
    int t = threadIdx.x;
    if (t == 0) ok = 1;
    if (t < 32) { sw[t] = W1[t]; sb[t] = b1[t]; }
    __syncthreads();
    int stride = E / 2048; if (stride < 1) stride = 1;
    bool bad = false;
#pragma unroll
    for (int i = 0; i < 8; ++i) {
        long k = (long)(t * 8 + i) * stride + 1;
        if (k < E && e32[2 * k + 1] != 0) bad = true;
    }
    if (bad) atomicAnd(&ok, 0);
    if (t < 64) {
        float up = 0.f, um = 0.f;
#pragma unroll
        for (int c = 0; c < 32; ++c) {
            float w = sw[c];
            float w2 = W2[c * 64 + t];
            up = fmaf(fmaxf(w, 0.f), w2, up);
            um = fmaf(fmaxf(-w, 0.f), w2, um);
        }
        upm[t] = up;
        upm[64 + t] = um;
    }
    __syncthreads();
    if (t == 0) {
        *flag = ok;   // 1 => int64 (shift 1), 0 => int32
        int z = 1;
        for (int c = 0; c < 32; ++c) if (sb[c] != 0.f) z = 0;
        *bzero = z;
    }
}

// per-chunk bucket histogram; stores the FULL row H[c][b] (no global atomics)
__global__ void k_hist2(const int* __restrict__ e32, const int* __restrict__ flag,
                        int E, int NSB, int chunk, int* __restrict__ H) {
    __shared__ int sh[NSBMAX];
    int c = blockIdx.x;
    int c0 = c * chunk;
    int c1 = c0 + chunk; if (c1 > E) c1 = E;
    for (int i = threadIdx.x; i < NSB; i += TPBW) sh[i] = 0;
    __syncthreads();
    int f = *flag;
    for (int e = c0 + threadIdx.x; e < c1; e += TPBW) {
        int d = e32[((long)E + e) << f];
        atomicAdd(&sh[d >> LBITS], 1);
    }
    __syncthreads();
    for (int i = threadIdx.x; i < NSB; i += TPBW) H[(size_t)c * NSB + i] = sh[i];
}

// per bucket: exclusive scan of H column over chunks -> P2; total -> colsum
__global__ void k_colscan(const int* __restrict__ H, int NSB,
                          int* __restrict__ P2, int* __restrict__ colsum) {
    __shared__ int s[NCHUNK];
    int b = blockIdx.x, t = threadIdx.x;
    int v = H[(size_t)t * NSB + b];
    s[t] = v;
    __syncthreads();
    for (int off = 1; off < NCHUNK; off <<= 1) {
        int x = s[t];
        int u = (t >= off) ? s[t - off] : 0;
        __syncthreads();
        s[t] = x + u;
        __syncthreads();
    }
    P2[(size_t)t * NSB + b] = s[t] - v;
    if (t == NCHUNK - 1) colsum[b] = s[t];
}

// one-block exclusive scan of NSB bucket totals -> base
__global__ void k_scan(const int* __restrict__ colsum, int NSB, int E,
                       int* __restrict__ base) {
    __shared__ int s[TPB];
    int K = (NSB + TPB - 1) / TPB;
    int t = threadIdx.x;
    int i0 = t * K;
    int tot = 0;
    for (int k = 0; k < K; ++k) { int i = i0 + k; if (i < NSB) tot += colsum[i]; }
    s[t] = tot;
    __syncthreads();
    for (int off = 1; off < TPB; off <<= 1) {
        int v = s[t];
        int u = (t >= off) ? s[t - off] : 0;
        __syncthreads();
        s[t] = v + u;
        __syncthreads();
    }
    int run = s[t] - tot;   // exclusive
    for (int k = 0; k < K; ++k) {
        int i = i0 + k;
        if (i < NSB) { base[i] = run; run += colsum[i]; }
    }
    if (t == 0) base[NSB] = E;
}

// partition edges bucket-major with DETERMINISTIC offsets: LDS cursor starts
// at base[b]+P2[c][b]; ONE LDS atomic per edge; clustered scatter of
// packed (ldst<<24)|src.
__global__ void k_part2(const int* __restrict__ e32, const int* __restrict__ flag,
                        int E, int NSB, const int* __restrict__ base,
                        const int* __restrict__ P2, unsigned int* __restrict__ P,
                        int chunk) {
    __shared__ int sh[NSBMAX];
    int c = blockIdx.x;
    int c0 = c * chunk;
    int c1 = c0 + chunk; if (c1 > E) c1 = E;
    for (int i = threadIdx.x; i < NSB; i += TPBW)
        sh[i] = base[i] + P2[(size_t)c * NSB + i];
    __syncthreads();
    int f = *flag;
    int sshift = 32 - LBITS;
    for (int e = c0 + threadIdx.x; e < c1; e += TPBW) {
        long ee = (long)e << f;
        int s = e32[ee];
        int d = e32[(((long)E) << f) + ee];
        int b = d >> LBITS;
        int pos = atomicAdd(&sh[b], 1);
        P[pos] = (unsigned)s | ((unsigned)(d & (SBSZ - 1)) << sshift);
    }
}

// per (bucket, quarter): LDS degree histogram -> plain partial store
__global__ void k_degS(const unsigned int* __restrict__ P, const int* __restrict__ base,
                       int n, int* __restrict__ cntP) {
    __shared__ int cnt[SBSZ];
    int bb = blockIdx.x / SPLIT, pp = blockIdx.x % SPLIT;
    int t = threadIdx.x;
    cnt[t] = 0;
    __syncthreads();
    int p0 = base[bb], len = base[bb + 1] - p0;
    int s0 = p0 + (int)((long)len * pp / SPLIT);
    int s1 = p0 + (int)((long)len * (pp + 1) / SPLIT);
    int sshift = 32 - LBITS;
    for (int p = s0 + t; p < s1; p += TPB)
        atomicAdd(&cnt[P[p] >> sshift], 1);
    __syncthreads();
    int v = (bb << LBITS) + t;
    if (v < n) cntP[pp * n + v] = cnt[t];
}

// node-parallel: cnt = sum partials -> dinv, g
__global__ void k_prep1(const int* __restrict__ cntP, const float* __restrict__ feat,
                        int n, float* __restrict__ dinv, float* __restrict__ g) {
    int v = blockIdx.x * TPB + threadIdx.x;
    if (v >= n) return;
    int c = 0;
#pragma unroll
    for (int pp = 0; pp < SPLIT; ++pp) c += cntP[pp * n + v];
    float di = rsqrtf((float)(c + 1));
    dinv[v] = di;
    g[v] = di * feat[v];
}

// per (bucket, quarter): partial A sums (LDS f32 atomics, 1/edge)
__global__ void k_aggAS(const unsigned int* __restrict__ P, const int* __restrict__ base,
                        int n, const float* __restrict__ g, float* __restrict__ AP) {
    __shared__ float A[SBSZ];
    int bb = blockIdx.x / SPLIT, pp = blockIdx.x % SPLIT;
    int t = threadIdx.x;
    A[t] = 0.f;
    __syncthreads();
    int p0 = base[bb], len = base[bb + 1] - p0;
    int s0 = p0 + (int)((long)len * pp / SPLIT);
    int s1 = p0 + (int)((long)len * (pp + 1) / SPLIT);
    int sshift = 32 - LBITS;
    unsigned smask = (1u << sshift) - 1;
    for (int p = s0 + t; p < s1; p += TPB) {
        unsigned e = P[p];
        atomicAdd(&A[e >> sshift], g[e & smask]);
    }
    __syncthreads();
    int v = (bb << LBITS) + t;
    if (v < n) AP[pp * n + v] = A[t];
}

// node-parallel: A = g_v + sum partials -> px -> signed qs = dinv*px; pd (fallback)
__global__ void k_prep2(const float* __restrict__ AP, const float* __restrict__ g,
                        const float* __restrict__ dinv, int n, const int* __restrict__ bzero,
                        float* __restrict__ qs, float2* __restrict__ pd,
                        float* __restrict__ Yagg) {
    int v = blockIdx.x * TPB + threadIdx.x;
    if (v >= n) return;
    float A = g[v];
#pragma unroll
    for (int pp = 0; pp < SPLIT; ++pp) A += AP[pp * n + v];
    float di = dinv[v];
    float px = di * A;
    qs[v] = di * px;
    if (!*bzero) {
        pd[v] = make_float2(px, di);
        float4* Y = (float4*)(Yagg + (size_t)v * 32);
#pragma unroll
        for (int i = 0; i < 8; ++i) Y[i] = make_float4(0.f, 0.f, 0.f, 0.f);
    }
}

// per (bucket, quarter): S± partials. ONE LDS atomic per edge (sign trick):
// only one of relu(±qs) is nonzero -> predicated address, |qs| value.
__global__ void k_aggTS(const unsigned int* __restrict__ P, const int* __restrict__ base,
                        int n, const float* __restrict__ qs, float2* __restrict__ SP2) {
    __shared__ float Sp[SBSZ], Sm[SBSZ];
    int bb = blockIdx.x / SPLIT, pp = blockIdx.x % SPLIT;
    int t = threadIdx.x;
    Sp[t] = 0.f; Sm[t] = 0.f;
    __syncthreads();
    int p0 = base[bb], len = base[bb + 1] - p0;
    int s0 = p0 + (int)((long)len * pp / SPLIT);
    int s1 = p0 + (int)((long)len * (pp + 1) / SPLIT);
    int sshift = 32 - LBITS;
    unsigned smask = (1u << sshift) - 1;
    for (int p = s0 + t; p < s1; p += TPB) {
        unsigned e = P[p];
        float q = qs[e & smask];
        int l = e >> sshift;
        float* addr = (q >= 0.f) ? &Sp[l] : &Sm[l];
        atomicAdd(addr, fabsf(q));
    }
    __syncthreads();
    int v = (bb << LBITS) + t;
    if (v < n) SP2[pp * n + v] = make_float2(Sp[t], Sm[t]);
}

// epilogue (fast, b1==0): thread per (v,k); S± = relu(±qs_v) + sum partials;
// out[v,k] = relu(dinv (S+ u+[k] + S- u-[k]) + b2[k]). Pure coalesced write.
__global__ void k_out(const float* __restrict__ qs, const float* __restrict__ dinv,
                      const float2* __restrict__ SP2, const float* __restrict__ upm,
                      const float* __restrict__ b2, const int* __restrict__ bzero,
                      int n, float* __restrict__ out) {
    if (!*bzero) return;
    __shared__ float su[192];    // u+ | u- | b2
    if (threadIdx.x < 192) su[threadIdx.x] = (threadIdx.x < 128) ? upm[threadIdx.x] : b2[threadIdx.x - 128];
    __syncthreads();
    int o = blockIdx.x * TPB + threadIdx.x;
    if (o >= n * 64) return;
    int v = o >> 6, k = o & 63;
    float qv = qs[v];
    float Sp = fmaxf(qv, 0.f), Sm = fmaxf(-qv, 0.f);
#pragma unroll
    for (int pp = 0; pp < SPLIT; ++pp) { float2 s = SP2[pp * n + v]; Sp += s.x; Sm += s.y; }
    float r = fmaf(dinv[v], fmaf(Sp, su[k], Sm * su[64 + k]), su[128 + k]);
    out[o] = fmaxf(r, 0.f);
}

// ---- general-b1 fallback (flag-gated; never taken in this bench) ----
__global__ void k_aggY(const int* __restrict__ e32, const int* __restrict__ flag,
                       int E, const int* __restrict__ bzero,
                       const float2* __restrict__ pd,
                       const float* __restrict__ W1, const float* __restrict__ b1,
                       float* __restrict__ Yagg) {
    if (*bzero) return;
    __shared__ float sw[32], sb[32];
    if (threadIdx.x < 32) { sw[threadIdx.x] = W1[threadIdx.x]; sb[threadIdx.x] = b1[threadIdx.x]; }
    __syncthreads();
    int sh = *flag;
    long stride = (long)gridDim.x * TPB;
    for (long e = (long)blockIdx.x * TPB + threadIdx.x; e < E; e += stride) {
        int s = e32[e << sh];
        int d = e32[((long)E + e) << sh];
        float2 p = pd[s];
#pragma unroll
        for (int c = 0; c < 32; ++c) {
            float y = p.y * fmaxf(fmaf(sw[c], p.x, sb[c] * p.y), 0.f);
            atomicAdd(&Yagg[(size_t)d * 32 + c], y);
        }
    }
}

__global__ void k_final_gen(const float2* __restrict__ pd, const float* __restrict__ Yagg,
                            const float* __restrict__ W1, const float* __restrict__ b1,
                            const float* __restrict__ W2, const float* __restrict__ b2,
                            const int* __restrict__ bzero, int n, float* __restrict__ out) {
    if (*bzero) return;
    __shared__ float sW[32 * 64];
    __shared__ float sb2[64];
    __shared__ float sagg[8][33];
    int t = threadIdx.x;
    for (int i = t; i < 32 * 64; i += TPB) sW[i] = W2[i];
    if (t < 64) sb2[t] = b2[t];
    int vl = t >> 5, c = t & 31;
    int nblk = (n + 7) / 8;
    for (int blk = blockIdx.x; blk < nblk; blk += gridDim.x) {
        int v = blk * 8 + vl;
        float a = 0.f;
        if (v < n) {
            float2 p = pd[v];
            float dv = p.y;
            float yv = fmaxf(fmaf(W1[c], p.x, b1[c] * p.y), 0.f);
            a = dv * (dv * yv + Yagg[(size_t)v * 32 + c]);
        }
        __syncthreads();
        sagg[vl][c] = a;
        __syncthreads();
        if (v < n) {
            float o0 = sb2[c], o1 = sb2[c + 32];
#pragma unroll
            for (int j = 0; j < 32; ++j) {
                float x = sagg[vl][j];
                o0 += x * sW[j * 64 + c];
                o1 += x * sW[j * 64 + 32 + c];
            }
            out[(size_t)v * 64 + c]      = fmaxf(o0, 0.f);
            out[(size_t)v * 64 + 32 + c] = fmaxf(o1, 0.f);
        }
    }
}

static inline size_t align256(size_t x) { return (x + 255) & ~(size_t)255; }

extern "C" void kernel_launch(void* const* d_in, const int* in_sizes, int n_in,
                              void* d_out, int out_size, void* d_ws, size_t ws_size,
                              hipStream_t stream) {
    const float* feat = (const float*)d_in[0];
    const int*   e32  = (const int*)d_in[1];
    const float* W1   = (const float*)d_in[2];
    const float* b1   = (const float*)d_in[3];
    const float* W2   = (const float*)d_in[4];
    const float* b2   = (const float*)d_in[5];
    float* out = (float*)d_out;

    int n = in_sizes[0];         // 100000
    int E = in_sizes[1] / 2;     // 3200000

    int NSB = (n + SBSZ - 1) >> LBITS;                    // 391 @ n=100K

    char* w = (char*)d_ws;
    size_t off = 0;
    auto alloc = [&](size_t bytes) -> char* { char* p = w + off; off = align256(off + bytes); return p; };
    unsigned int* P = (unsigned int*)alloc((size_t)E * 4);
    int*    H     = (int*)alloc((size_t)NCHUNK * NSB * 4);
    int*    P2    = (int*)alloc((size_t)NCHUNK * NSB * 4);
    int*    colsum= (int*)alloc((size_t)NSB * 4);
    int*    base  = (int*)alloc((size_t)(NSB + 1) * 4);
    int*    cntP  = (int*)alloc((size_t)SPLIT * n * 4);
    float*  AP    = (float*)alloc((size_t)SPLIT * n * 4);
    float2* SP2   = (float2*)alloc((size_t)SPLIT * n * 8);
    float*  dinv  = (float*)alloc((size_t)n * 4);
    float*  g     = (float*)alloc((size_t)n * 4);
    float*  qs    = (float*)alloc((size_t)n * 4);
    float2* pd    = (float2*)alloc((size_t)n * 8);
    float*  upm   = (float*)alloc(128 * 4);
    int*    flag  = (int*)alloc(4);
    int*    bzero = (int*)alloc(4);
    float*  Yagg  = (float*)alloc((size_t)n * 32 * 4);    // general path only

    int chunk = (E + NCHUNK - 1) / NCHUNK;
    int gN = (n + TPB - 1) / TPB;
    int gS = NSB * SPLIT;
    int gO = (n * 64 + TPB - 1) / TPB;

    hipLaunchKernelGGL(k_init,      dim3(1),      dim3(TPB),  0, stream, e32, E, flag, W1, b1, W2, upm, bzero);
    hipLaunchKernelGGL(k_hist2,     dim3(NCHUNK), dim3(TPBW), 0, stream, e32, flag, E, NSB, chunk, H);
    hipLaunchKernelGGL(k_colscan,   dim3(NSB),    dim3(NCHUNK), 0, stream, H, NSB, P2, colsum);
    hipLaunchKernelGGL(k_scan,      dim3(1),      dim3(TPB),  0, stream, colsum, NSB, E, base);
    hipLaunchKernelGGL(k_part2,     dim3(NCHUNK), dim3(TPBW), 0, stream, e32, flag, E, NSB, base, P2, P, chunk);
    hipLaunchKernelGGL(k_degS,      dim3(gS),     dim3(TPB),  0, stream, P, base, n, cntP);
    hipLaunchKernelGGL(k_prep1,     dim3(gN),     dim3(TPB),  0, stream, cntP, feat, n, dinv, g);
    hipLaunchKernelGGL(k_aggAS,     dim3(gS),     dim3(TPB),  0, stream, P, base, n, g, AP);
    hipLaunchKernelGGL(k_prep2,     dim3(gN),     dim3(TPB),  0, stream, AP, g, dinv, n, bzero, qs, pd, Yagg);
    hipLaunchKernelGGL(k_aggTS,     dim3(gS),     dim3(TPB),  0, stream, P, base, n, qs, SP2);
    hipLaunchKernelGGL(k_out,       dim3(gO),     dim3(TPB),  0, stream, qs, dinv, SP2, upm, b2, bzero, n, out);
    hipLaunchKernelGGL(k_aggY,      dim3(512),    dim3(TPB),  0, stream, e32, flag, E, bzero, pd, W1, b1, Yagg);
    hipLaunchKernelGGL(k_final_gen, dim3(1024),   dim3(TPB),  0, stream, pd, Yagg, W1, b1, W2, b2, bzero, n, out);
}